// Round 1
// baseline (107.991 us; speedup 1.0000x reference)
//
#include <hip/hip_runtime.h>
#include <math.h>

#define ROWS 512
#define DIM 2048
#define MS 51            // MAX_SHIFT
#define NWIN 103         // 2*MS+1
#define KMIN 32          // HIGHPASS bins
#define NMASK 993        // 1025-32
#define PHYS(i) ((i) + ((i) >> 5))

// ------------------------------------------------------------------
// Kernel 1: center x_hat, compute shifted-Pearson max -> loss0[row],
// and write centered signal (yhat) to ws for the FFT kernel.
// One block (256 threads) per row.
// ------------------------------------------------------------------
__global__ __launch_bounds__(256) void prep_corr_kernel(
    const float* __restrict__ xhat, const float* __restrict__ x,
    float* __restrict__ yhat_out, float* __restrict__ loss0)
{
    const int r = blockIdx.x;
    const int t = threadIdx.x;
    const int lane = t & 63;
    const int wave = t >> 6;
    const float* xh = xhat + (size_t)r * DIM;
    const float* xr = x + (size_t)r * DIM;

    __shared__ float yh[PHYS(2149) + 1];   // padded centered x_hat, logical [0,2150)
    __shared__ float yc[PHYS(2047) + 1];   // x - mean(x)
    __shared__ float red[32];
    __shared__ float sc[8];
    __shared__ float headS[MS + 1], headQ[MS + 1], tailS[MS + 1], tailQ[MS + 1];

    float4 a0 = ((const float4*)xh)[2 * t];
    float4 a1 = ((const float4*)xh)[2 * t + 1];
    float4 b0 = ((const float4*)xr)[2 * t];
    float4 b1 = ((const float4*)xr)[2 * t + 1];
    float av[8] = {a0.x, a0.y, a0.z, a0.w, a1.x, a1.y, a1.z, a1.w};
    float bv[8] = {b0.x, b0.y, b0.z, b0.w, b1.x, b1.y, b1.z, b1.w};

    // min/max of x_hat, sum of x
    float mn = av[0], mx = av[0], sx = 0.f;
#pragma unroll
    for (int j = 0; j < 8; ++j) {
        mn = fminf(mn, av[j]); mx = fmaxf(mx, av[j]); sx += bv[j];
    }
#pragma unroll
    for (int d = 32; d; d >>= 1) {
        mn = fminf(mn, __shfl_down(mn, d));
        mx = fmaxf(mx, __shfl_down(mx, d));
        sx += __shfl_down(sx, d);
    }
    if (lane == 0) { red[wave] = mn; red[8 + wave] = mx; red[16 + wave] = sx; }
    __syncthreads();
    if (t == 0) {
        sc[0] = fminf(fminf(red[0], red[1]), fminf(red[2], red[3]));
        sc[1] = fmaxf(fmaxf(red[8], red[9]), fmaxf(red[10], red[11]));
        sc[2] = (red[16] + red[17] + red[18] + red[19]) * (1.0f / DIM);
    }
    __syncthreads();
    mn = sc[0]; mx = sc[1];
    const float mean = sc[2];
    const float scale = 2.0f / (mx - mn);

    // center, write LDS (+ global yhat), accumulate S1,S2,Syy
    float s1 = 0.f, s2 = 0.f, syy = 0.f;
    float yhv[8], ycv[8];
#pragma unroll
    for (int j = 0; j < 8; ++j) {
        float y = (av[j] - mn) * scale - 1.0f;
        float z = bv[j] - mean;
        yhv[j] = y; ycv[j] = z;
        s1 += y; s2 += y * y; syy += z * z;
        int i = 8 * t + j;
        yh[PHYS(i + MS)] = y;
        yc[PHYS(i)] = z;
    }
    {
        float4* yo = (float4*)(yhat_out + (size_t)r * DIM);
        yo[2 * t] = make_float4(yhv[0], yhv[1], yhv[2], yhv[3]);
        yo[2 * t + 1] = make_float4(yhv[4], yhv[5], yhv[6], yhv[7]);
    }
    if (t < MS) { yh[PHYS(t)] = 0.f; yh[PHYS(t + MS + DIM)] = 0.f; }  // zero pads

#pragma unroll
    for (int d = 32; d; d >>= 1) {
        s1 += __shfl_down(s1, d); s2 += __shfl_down(s2, d); syy += __shfl_down(syy, d);
    }
    if (lane == 0) { red[wave] = s1; red[8 + wave] = s2; red[16 + wave] = syy; }
    __syncthreads();
    if (t == 0) {
        sc[3] = red[0] + red[1] + red[2] + red[3];
        sc[4] = red[8] + red[9] + red[10] + red[11];
        sc[5] = red[16] + red[17] + red[18] + red[19];
    }
    __syncthreads();
    const float S1 = sc[3], S2 = sc[4], Syy = sc[5];

    // head/tail prefix sums of yhat (for window sum / sumsq at each lag)
    if (t < MS + 1) {
        float hs = 0.f, hq = 0.f, ts = 0.f, tq = 0.f;
        for (int j = 0; j < t; ++j) {
            float v = yh[PHYS(MS + j)];            hs += v; hq += v * v;
            float w = yh[PHYS(MS + DIM - 1 - j)];  ts += w; tq += w * w;
        }
        headS[t] = hs; headQ[t] = hq; tailS[t] = ts; tailQ[t] = tq;
    }
    __syncthreads();

    // yc chunk in registers: lane covers t-range [32*lane, 32*lane+32)
    float ycr[32];
#pragma unroll
    for (int j = 0; j < 32; ++j) ycr[j] = yc[PHYS(32 * lane + j)];

    // each wave handles lags c = wave, wave+4, ... (c = off + MS)
    float cmax = -2.0f;
    for (int c = wave; c < NWIN; c += 4) {
        int base = 32 * lane + c;
        float acc = 0.f;
#pragma unroll
        for (int j = 0; j < 32; ++j) {
            int i = base + j;
            acc += yh[PHYS(i)] * ycr[j];
        }
#pragma unroll
        for (int d = 32; d; d >>= 1) acc += __shfl_down(acc, d);
        if (lane == 0) {
            int off = c - MS;
            float sw, qw;
            if (off >= 0) { sw = S1 - headS[off]; qw = S2 - headQ[off]; }
            else          { sw = S1 - tailS[-off]; qw = S2 - tailQ[-off]; }
            float varw = qw - sw * sw * (1.0f / DIM);
            float corr = acc / sqrtf(varw * Syy);
            cmax = fmaxf(cmax, corr);
        }
    }
    if (lane == 0) red[wave] = cmax;
    __syncthreads();
    if (t == 0) {
        float m = fmaxf(fmaxf(red[0], red[1]), fmaxf(red[2], red[3]));
        loss0[r] = (1.0f - m) / (1.0f + m);
    }
}

// ------------------------------------------------------------------
// Kernel 2: 2048-pt Stockham radix-2 FFT (complex, imag=0 input),
// emit |X[k]|/2048 for k in [32,1025). One block per (row, signal).
// ------------------------------------------------------------------
__global__ __launch_bounds__(256) void fft_mag_kernel(
    const float* __restrict__ yhat, const float* __restrict__ x,
    float* __restrict__ mags)
{
    const int bid = blockIdx.x;
    const int r = bid >> 1, which = bid & 1;
    const float* src = which ? (x + (size_t)r * DIM) : (yhat + (size_t)r * DIM);
    const int t = threadIdx.x;

    __shared__ float Ar[2048], Ai[2048], Br[2048], Bi[2048];

#pragma unroll
    for (int k = 0; k < 8; ++k) {
        int i = t + 256 * k;
        Ar[i] = src[i]; Ai[i] = 0.f;
    }
    __syncthreads();

    float *sr = Ar, *si = Ai, *dr = Br, *di = Bi;
    for (int stage = 0; stage < 11; ++stage) {
        const int s = 1 << stage;
#pragma unroll
        for (int k = 0; k < 4; ++k) {
            int b = t + 256 * k;           // butterfly id in [0,1024)
            int u = b & ~(s - 1);          // = p*s
            float ar = sr[b],        ai = si[b];
            float br = sr[b + 1024], bi = si[b + 1024];
            float ang = (float)u * (-3.14159265358979323846f / 1024.0f);
            float cw, sw;
            sincosf(ang, &sw, &cw);
            float xr = ar - br, xi = ai - bi;
            dr[b + u]     = ar + br;
            di[b + u]     = ai + bi;
            dr[b + u + s] = xr * cw - xi * sw;
            di[b + u + s] = xr * sw + xi * cw;
        }
        __syncthreads();
        float* tmp;
        tmp = sr; sr = dr; dr = tmp;
        tmp = si; si = di; di = tmp;
    }
    // result (natural order) now in sr/si
    float* out = mags + (size_t)bid * NMASK;
    for (int k = t; k < NMASK; k += 256) {
        int f = k + KMIN;
        float re = sr[f], im = si[f];
        out[k] = sqrtf(re * re + im * im) * (1.0f / 2048.0f);
    }
}

// ------------------------------------------------------------------
// Kernel 3: chisq (two 993-elem scans + searchsorted + 16 bins),
// combine with loss0 -> d_out. One block per row.
// ------------------------------------------------------------------
__global__ __launch_bounds__(256) void chisq_kernel(
    const float* __restrict__ mags, const float* __restrict__ loss0,
    float* __restrict__ out)
{
    const int r = blockIdx.x;
    const int t = threadIdx.x;
    const int lane = t & 63;
    const int wave = t >> 6;
    const float* mh = mags + (size_t)(2 * r) * NMASK;
    const float* ms = mags + (size_t)(2 * r + 1) * NMASK;

    __shared__ float siA[1024];
    __shared__ float siB[1024];
    __shared__ float wsum[4];
    __shared__ int edges[17];
    __shared__ float summ[16];

    float h[4], s[4];
#pragma unroll
    for (int j = 0; j < 4; ++j) {
        int k = 4 * t + j;
        h[j] = (k < NMASK) ? mh[k] : 0.f;
        s[j] = (k < NMASK) ? ms[k] : 0.f;
    }

    // ---- scan A: si = cumsum(4*|h|^2) ----
    float e0 = 4.f * h[0] * h[0];
    float e1 = e0 + 4.f * h[1] * h[1];
    float e2 = e1 + 4.f * h[2] * h[2];
    float e3 = e2 + 4.f * h[3] * h[3];
    float tot = e3;
    float inc = tot;
#pragma unroll
    for (int d = 1; d < 64; d <<= 1) {
        float y = __shfl_up(inc, d);
        if (lane >= d) inc += y;
    }
    if (lane == 63) wsum[wave] = inc;
    __syncthreads();
    float woff = 0.f;
    for (int w = 0; w < wave; ++w) woff += wsum[w];
    float pre = woff + inc - tot;
    siA[4 * t + 0] = pre + e0;
    siA[4 * t + 1] = pre + e1;
    siA[4 * t + 2] = pre + e2;
    siA[4 * t + 3] = pre + e3;
    __syncthreads();
    const float total = siA[NMASK - 1];

    // ---- edges: searchsorted(si, i/16*total, side='right'), clipped ----
    if (t < 17) {
        float bin = ((float)t * (1.0f / 16.0f)) * total;
        int lo = 0, hi = NMASK;
        while (lo < hi) {
            int mid = (lo + hi) >> 1;
            if (siA[mid] <= bin) lo = mid + 1; else hi = mid;
        }
        edges[t] = (lo < NMASK - 1) ? lo : (NMASK - 1);
    }

    // ---- scan B: si2 = cumsum(4*|h||s|/sqrt(total)) ----
    const float q = 1.0f / sqrtf(total);
    float g0 = 4.f * h[0] * s[0] * q;
    float g1 = g0 + 4.f * h[1] * s[1] * q;
    float g2 = g1 + 4.f * h[2] * s[2] * q;
    float g3 = g2 + 4.f * h[3] * s[3] * q;
    float tot2l = g3;
    float inc2 = tot2l;
#pragma unroll
    for (int d = 1; d < 64; d <<= 1) {
        float y = __shfl_up(inc2, d);
        if (lane >= d) inc2 += y;
    }
    if (lane == 63) wsum[wave] = inc2;   // woff reads above completed before last barrier
    __syncthreads();
    float woff2 = 0.f;
    for (int w = 0; w < wave; ++w) woff2 += wsum[w];
    float pre2 = woff2 + inc2 - tot2l;
    siB[4 * t + 0] = pre2 + g0;
    siB[4 * t + 1] = pre2 + g1;
    siB[4 * t + 2] = pre2 + g2;
    siB[4 * t + 3] = pre2 + g3;
    __syncthreads();
    const float total2 = siB[NMASK - 1];

    if (t < 16) {
        float snr = siB[edges[t + 1]] - siB[edges[t]];
        float d = snr - total2 * (1.0f / 16.0f);
        summ[t] = d * d;
    }
    __syncthreads();
    if (t == 0) {
        float ssum = 0.f;
        for (int i = 0; i < 16; ++i) ssum += summ[i];
        float chisq = 16.0f * ssum / 15.0f;
        float c3 = chisq * chisq * chisq;
        out[r] = loss0[r] * powf(1.0f + c3, 1.0f / 6.0f);
    }
}

// ------------------------------------------------------------------
extern "C" void kernel_launch(void* const* d_in, const int* in_sizes, int n_in,
                              void* d_out, int out_size, void* d_ws, size_t ws_size,
                              hipStream_t stream) {
    const float* xhat = (const float*)d_in[0];
    const float* x    = (const float*)d_in[1];
    float* out = (float*)d_out;
    float* ws = (float*)d_ws;

    float* loss0 = ws;                              // 512 floats
    float* yhat  = ws + 512;                        // 512*2048 floats
    float* mags  = yhat + (size_t)ROWS * DIM;       // 512*2*993 floats

    prep_corr_kernel<<<ROWS, 256, 0, stream>>>(xhat, x, yhat, loss0);
    fft_mag_kernel<<<ROWS * 2, 256, 0, stream>>>(yhat, x, mags);
    chisq_kernel<<<ROWS, 256, 0, stream>>>(mags, loss0, out);
}

// Round 2
// 93.009 us; speedup vs baseline: 1.1611x; 1.1611x over previous
//
#include <hip/hip_runtime.h>
#include <math.h>

#define ROWS 512
#define DIM 2048
#define MS 51            // MAX_SHIFT
#define NWIN 103         // 2*MS+1
#define KMIN 32          // HIGHPASS bins
#define NMASK 993        // 1025-32
#define PHYS(i) ((i) + ((i) >> 5))

// Fused kernel: one block (256 threads) per row.
//  Phase P: center x_hat, shifted-Pearson max over 103 lags -> loss0 (in LDS)
//  Phase F: one packed complex FFT (z = yhat + i*x), twiddle table in LDS
//  Phase C: Hermitian unpack -> |H|,|S|; two 993-elem scans; searchsorted;
//           16-bin chisq; combine -> out[r]
__global__ __launch_bounds__(256) void fused_mfl_kernel(
    const float* __restrict__ xhat, const float* __restrict__ x,
    float* __restrict__ out)
{
    const int r = blockIdx.x;
    const int t = threadIdx.x;
    const int lane = t & 63;
    const int wave = t >> 6;
    const float* xh = xhat + (size_t)r * DIM;
    const float* xr = x + (size_t)r * DIM;

    // 40 KB arena, aliased across phases
    __shared__ float smem[10240];
    // Phase P carve
    float* yh    = smem;            // PHYS(2149)+1 = 2217 -> 2224
    float* yc    = smem + 2224;     // PHYS(2047)+1 = 2111 -> 2112
    float* headS = smem + 4336;
    float* headQ = smem + 4388;
    float* tailS = smem + 4440;
    float* tailQ = smem + 4492;
    // Phase F carve
    float* Ar  = smem;
    float* Ai  = smem + 2048;
    float* Br  = smem + 4096;
    float* Bi  = smem + 6144;
    float* twr = smem + 8192;
    float* twi = smem + 9216;
    // Phase C carve (A-buffers are dead after the final (11th, odd) stage)
    float* siA = smem;              // 1024
    float* siB = smem + 2048;       // 1024

    __shared__ float red[32];
    __shared__ float sc[8];
    __shared__ int   edges[17];
    __shared__ float summ[16];
    __shared__ float wsum[4];

    // ---------------- load inputs (kept in registers across phases) --------
    float4 a0 = ((const float4*)xh)[2 * t];
    float4 a1 = ((const float4*)xh)[2 * t + 1];
    float4 b0 = ((const float4*)xr)[2 * t];
    float4 b1 = ((const float4*)xr)[2 * t + 1];
    float av[8] = {a0.x, a0.y, a0.z, a0.w, a1.x, a1.y, a1.z, a1.w};
    float bv[8] = {b0.x, b0.y, b0.z, b0.w, b1.x, b1.y, b1.z, b1.w};

    // ---------------- Phase P: center + shifted Pearson --------------------
    float mn = av[0], mx = av[0], sx = 0.f;
#pragma unroll
    for (int j = 0; j < 8; ++j) {
        mn = fminf(mn, av[j]); mx = fmaxf(mx, av[j]); sx += bv[j];
    }
#pragma unroll
    for (int d = 32; d; d >>= 1) {
        mn = fminf(mn, __shfl_down(mn, d));
        mx = fmaxf(mx, __shfl_down(mx, d));
        sx += __shfl_down(sx, d);
    }
    if (lane == 0) { red[wave] = mn; red[8 + wave] = mx; red[16 + wave] = sx; }
    __syncthreads();
    if (t == 0) {
        sc[0] = fminf(fminf(red[0], red[1]), fminf(red[2], red[3]));
        sc[1] = fmaxf(fmaxf(red[8], red[9]), fmaxf(red[10], red[11]));
        sc[2] = (red[16] + red[17] + red[18] + red[19]) * (1.0f / DIM);
    }
    __syncthreads();
    mn = sc[0]; mx = sc[1];
    const float mean = sc[2];
    const float scale = 2.0f / (mx - mn);

    float s1 = 0.f, s2 = 0.f, syy = 0.f;
    float yhv[8];
#pragma unroll
    for (int j = 0; j < 8; ++j) {
        float y = (av[j] - mn) * scale - 1.0f;
        float z = bv[j] - mean;
        yhv[j] = y;
        s1 += y; s2 += y * y; syy += z * z;
        int i = 8 * t + j;
        yh[PHYS(i + MS)] = y;
        yc[PHYS(i)] = z;
    }
    if (t < MS) { yh[PHYS(t)] = 0.f; yh[PHYS(t + MS + DIM)] = 0.f; }

#pragma unroll
    for (int d = 32; d; d >>= 1) {
        s1 += __shfl_down(s1, d); s2 += __shfl_down(s2, d); syy += __shfl_down(syy, d);
    }
    if (lane == 0) { red[wave] = s1; red[8 + wave] = s2; red[16 + wave] = syy; }
    __syncthreads();
    if (t == 0) {
        sc[3] = red[0] + red[1] + red[2] + red[3];
        sc[4] = red[8] + red[9] + red[10] + red[11];
        sc[5] = red[16] + red[17] + red[18] + red[19];
    }
    __syncthreads();
    const float S1 = sc[3], S2 = sc[4], Syy = sc[5];

    if (t < MS + 1) {
        float hs = 0.f, hq = 0.f, ts = 0.f, tq = 0.f;
        for (int j = 0; j < t; ++j) {
            float v = yh[PHYS(MS + j)];            hs += v; hq += v * v;
            float w = yh[PHYS(MS + DIM - 1 - j)];  ts += w; tq += w * w;
        }
        headS[t] = hs; headQ[t] = hq; tailS[t] = ts; tailQ[t] = tq;
    }
    __syncthreads();

    float ycr[32];
#pragma unroll
    for (int j = 0; j < 32; ++j) ycr[j] = yc[PHYS(32 * lane + j)];

    float cmax = -2.0f;
    for (int c = wave; c < NWIN; c += 4) {
        int base = 32 * lane + c;
        float acc = 0.f;
#pragma unroll
        for (int j = 0; j < 32; ++j) {
            int i = base + j;
            acc += yh[PHYS(i)] * ycr[j];
        }
#pragma unroll
        for (int d = 32; d; d >>= 1) acc += __shfl_down(acc, d);
        if (lane == 0) {
            int off = c - MS;
            float sw, qw;
            if (off >= 0) { sw = S1 - headS[off]; qw = S2 - headQ[off]; }
            else          { sw = S1 - tailS[-off]; qw = S2 - tailQ[-off]; }
            float varw = qw - sw * sw * (1.0f / DIM);
            float corr = acc / sqrtf(varw * Syy);
            cmax = fmaxf(cmax, corr);
        }
    }
    if (lane == 0) red[wave] = cmax;
    __syncthreads();
    if (t == 0) {
        float m = fmaxf(fmaxf(red[0], red[1]), fmaxf(red[2], red[3]));
        sc[6] = (1.0f - m) / (1.0f + m);     // loss0, survives in non-aliased LDS
    }
    __syncthreads();   // everyone done with Phase-P smem before overwrite

    // ---------------- Phase F: packed complex FFT ---------------------------
    // twiddle table: tw[u] = exp(-i*pi*u/1024), u in [0,1024)
#pragma unroll
    for (int k = 0; k < 4; ++k) {
        int u = t + 256 * k;
        float cw, sw;
        sincosf((float)u * (-3.14159265358979323846f / 1024.0f), &sw, &cw);
        twr[u] = cw; twi[u] = sw;
    }
    // z = yhat + i*x, from registers
#pragma unroll
    for (int j = 0; j < 8; ++j) {
        int i = 8 * t + j;
        Ar[i] = yhv[j];
        Ai[i] = bv[j];
    }
    __syncthreads();

    float *sr = Ar, *si_ = Ai, *dr = Br, *di = Bi;
    for (int stage = 0; stage < 11; ++stage) {
        const int s = 1 << stage;
#pragma unroll
        for (int k = 0; k < 4; ++k) {
            int b = t + 256 * k;           // butterfly id in [0,1024)
            int u = b & ~(s - 1);
            float ar = sr[b],        ai = si_[b];
            float br = sr[b + 1024], bi = si_[b + 1024];
            float cw = twr[u], sw = twi[u];
            float xr2 = ar - br, xi2 = ai - bi;
            dr[b + u]     = ar + br;
            di[b + u]     = ai + bi;
            dr[b + u + s] = xr2 * cw - xi2 * sw;
            di[b + u + s] = xr2 * sw + xi2 * cw;
        }
        __syncthreads();
        float* tmp;
        tmp = sr; sr = dr; dr = tmp;
        tmp = si_; si_ = di; di = tmp;
    }
    // 11 stages (odd) -> final data in Br/Bi; sr/si_ point there.

    // ---------------- Phase C: unpack + chisq -------------------------------
    const float MSC = 0.5f * (1.0f / 2048.0f);
    float h[4], sg[4];
#pragma unroll
    for (int j = 0; j < 4; ++j) {
        int m = 4 * t + j;
        if (m < NMASK) {
            int f = m + KMIN;
            int g = 2048 - f;
            float zrf = sr[f], zif = si_[f];
            float zrg = sr[g], zig = si_[g];
            float hre = zrf + zrg, him = zif - zig;
            float sre = zif + zig, sim = zrg - zrf;
            h[j]  = sqrtf(hre * hre + him * him) * MSC;
            sg[j] = sqrtf(sre * sre + sim * sim) * MSC;
        } else { h[j] = 0.f; sg[j] = 0.f; }
    }
    // scans write to siA/siB = A-buffers (disjoint from Br/Bi) — no hazard.

    // ---- scan A: si = cumsum(4*|h|^2) ----
    float e0 = 4.f * h[0] * h[0];
    float e1 = e0 + 4.f * h[1] * h[1];
    float e2 = e1 + 4.f * h[2] * h[2];
    float e3 = e2 + 4.f * h[3] * h[3];
    float tot = e3;
    float inc = tot;
#pragma unroll
    for (int d = 1; d < 64; d <<= 1) {
        float y = __shfl_up(inc, d);
        if (lane >= d) inc += y;
    }
    if (lane == 63) wsum[wave] = inc;
    __syncthreads();
    float woff = 0.f;
    for (int w = 0; w < wave; ++w) woff += wsum[w];
    float pre = woff + inc - tot;
    siA[4 * t + 0] = pre + e0;
    siA[4 * t + 1] = pre + e1;
    siA[4 * t + 2] = pre + e2;
    siA[4 * t + 3] = pre + e3;
    __syncthreads();
    const float total = siA[NMASK - 1];

    if (t < 17) {
        float bin = ((float)t * (1.0f / 16.0f)) * total;
        int lo = 0, hi = NMASK;
        while (lo < hi) {
            int mid = (lo + hi) >> 1;
            if (siA[mid] <= bin) lo = mid + 1; else hi = mid;
        }
        edges[t] = (lo < NMASK - 1) ? lo : (NMASK - 1);
    }

    // ---- scan B: si2 = cumsum(4*|h||s|/sqrt(total)) ----
    const float q = 1.0f / sqrtf(total);
    float g0 = 4.f * h[0] * sg[0] * q;
    float g1 = g0 + 4.f * h[1] * sg[1] * q;
    float g2 = g1 + 4.f * h[2] * sg[2] * q;
    float g3 = g2 + 4.f * h[3] * sg[3] * q;
    float tot2l = g3;
    float inc2 = tot2l;
#pragma unroll
    for (int d = 1; d < 64; d <<= 1) {
        float y = __shfl_up(inc2, d);
        if (lane >= d) inc2 += y;
    }
    if (lane == 63) wsum[wave] = inc2;
    __syncthreads();
    float woff2 = 0.f;
    for (int w = 0; w < wave; ++w) woff2 += wsum[w];
    float pre2 = woff2 + inc2 - tot2l;
    siB[4 * t + 0] = pre2 + g0;
    siB[4 * t + 1] = pre2 + g1;
    siB[4 * t + 2] = pre2 + g2;
    siB[4 * t + 3] = pre2 + g3;
    __syncthreads();
    const float total2 = siB[NMASK - 1];

    if (t < 16) {
        float snr = siB[edges[t + 1]] - siB[edges[t]];
        float d = snr - total2 * (1.0f / 16.0f);
        summ[t] = d * d;
    }
    __syncthreads();
    if (t == 0) {
        float ssum = 0.f;
        for (int i = 0; i < 16; ++i) ssum += summ[i];
        float chisq = 16.0f * ssum / 15.0f;
        float c3 = chisq * chisq * chisq;
        out[r] = sc[6] * powf(1.0f + c3, 1.0f / 6.0f);
    }
}

// ------------------------------------------------------------------
extern "C" void kernel_launch(void* const* d_in, const int* in_sizes, int n_in,
                              void* d_out, int out_size, void* d_ws, size_t ws_size,
                              hipStream_t stream) {
    const float* xhat = (const float*)d_in[0];
    const float* x    = (const float*)d_in[1];
    float* out = (float*)d_out;
    (void)d_ws; (void)ws_size;

    fused_mfl_kernel<<<ROWS, 256, 0, stream>>>(xhat, x, out);
}

// Round 3
// 77.825 us; speedup vs baseline: 1.3876x; 1.1951x over previous
//
#include <hip/hip_runtime.h>
#include <math.h>

#define ROWS 512
#define DIM 2048
#define MS 51            // MAX_SHIFT
#define NWIN 103         // 2*MS+1
#define KMIN 32          // HIGHPASS bins
#define NMASK 993        // 1025-32
#define PHYS(i) ((i) + ((i) >> 5))

// One block (256 threads) per row.
//  Phase P: center x_hat, shifted-Pearson max (sliding register window)
//  Phase F: packed complex FFT z = yhat + i*x, radix-4 Stockham x5 + radix-2
//  Phase C: Hermitian unpack -> |H|,|S|; two 993-elem scans; searchsorted;
//           16-bin chisq; combine -> out[r]
__global__ __launch_bounds__(256) void fused_mfl_kernel(
    const float* __restrict__ xhat, const float* __restrict__ x,
    float* __restrict__ out)
{
    const int r = blockIdx.x;
    const int t = threadIdx.x;
    const int lane = t & 63;
    const int wave = t >> 6;
    const float* xh = xhat + (size_t)r * DIM;
    const float* xr = x + (size_t)r * DIM;

    // 36 KB arena, aliased across phases
    __shared__ float smem[9216];
    // Phase P carve (all inside [0, 4560) )
    float* yh    = smem;            // PHYS(2149)+1 = 2217 floats
    float* yc    = smem + 2224;     // PHYS(2047)+1 = 2111 floats
    float* headS = smem + 4352;     // 52
    float* headQ = smem + 4404;     // 52
    float* tailS = smem + 4456;     // 52
    float* tailQ = smem + 4508;     // 52   (ends 4560)
    // Phase F carve
    float2* A  = (float2*)smem;             // 2048 cplx  [0,4096) floats
    float2* Bb = (float2*)(smem + 4096);    // 2048 cplx  [4096,8192)
    float2* TW = (float2*)(smem + 8192);    // 512 cplx   [8192,9216)
    // Phase C carve (B region is dead: 6 stages -> final data in A)
    float* siA = smem + 4096;       // 1024
    float* siB = smem + 5120;       // 1024

    __shared__ float red[32];
    __shared__ float sc[8];
    __shared__ int   edges[17];
    __shared__ float summ[16];
    __shared__ float wsum[4];

    // ---------------- load inputs (kept in registers across phases) --------
    float4 a0 = ((const float4*)xh)[2 * t];
    float4 a1 = ((const float4*)xh)[2 * t + 1];
    float4 b0 = ((const float4*)xr)[2 * t];
    float4 b1 = ((const float4*)xr)[2 * t + 1];
    float av[8] = {a0.x, a0.y, a0.z, a0.w, a1.x, a1.y, a1.z, a1.w};
    float bv[8] = {b0.x, b0.y, b0.z, b0.w, b1.x, b1.y, b1.z, b1.w};

    // twiddle table (region untouched until FFT): TW[u] = exp(-i*pi*u/1024)
#pragma unroll
    for (int k = 0; k < 2; ++k) {
        int u = t + 256 * k;
        float swv, cwv;
        sincosf((float)u * (-3.14159265358979323846f / 1024.0f), &swv, &cwv);
        TW[u] = make_float2(cwv, swv);
    }

    // ---------------- Phase P: center + shifted Pearson --------------------
    float mn = av[0], mx = av[0], sx = 0.f;
#pragma unroll
    for (int j = 0; j < 8; ++j) {
        mn = fminf(mn, av[j]); mx = fmaxf(mx, av[j]); sx += bv[j];
    }
#pragma unroll
    for (int d = 32; d; d >>= 1) {
        mn = fminf(mn, __shfl_down(mn, d));
        mx = fmaxf(mx, __shfl_down(mx, d));
        sx += __shfl_down(sx, d);
    }
    if (lane == 0) { red[wave] = mn; red[8 + wave] = mx; red[16 + wave] = sx; }
    __syncthreads();
    if (t == 0) {
        sc[0] = fminf(fminf(red[0], red[1]), fminf(red[2], red[3]));
        sc[1] = fmaxf(fmaxf(red[8], red[9]), fmaxf(red[10], red[11]));
        sc[2] = (red[16] + red[17] + red[18] + red[19]) * (1.0f / DIM);
    }
    __syncthreads();
    mn = sc[0]; mx = sc[1];
    const float mean = sc[2];
    const float scale = 2.0f / (mx - mn);

    float s1 = 0.f, s2 = 0.f, syy = 0.f;
    float yhv[8];
#pragma unroll
    for (int j = 0; j < 8; ++j) {
        float y = (av[j] - mn) * scale - 1.0f;
        float z = bv[j] - mean;
        yhv[j] = y;
        s1 += y; s2 += y * y; syy += z * z;
        int i = 8 * t + j;
        yh[PHYS(i + MS)] = y;
        yc[PHYS(i)] = z;
    }
    if (t < MS) { yh[PHYS(t)] = 0.f; yh[PHYS(t + MS + DIM)] = 0.f; }

#pragma unroll
    for (int d = 32; d; d >>= 1) {
        s1 += __shfl_down(s1, d); s2 += __shfl_down(s2, d); syy += __shfl_down(syy, d);
    }
    if (lane == 0) { red[wave] = s1; red[8 + wave] = s2; red[16 + wave] = syy; }
    __syncthreads();
    if (t == 0) {
        sc[3] = red[0] + red[1] + red[2] + red[3];
        sc[4] = red[8] + red[9] + red[10] + red[11];
        sc[5] = red[16] + red[17] + red[18] + red[19];
    }
    __syncthreads();
    const float S1 = sc[3], S2 = sc[4], Syy = sc[5];

    // head/tail exclusive prefix sums, wave-parallel (waves 0 and 1)
    if (wave < 2) {
        float v = 0.f;
        if (lane >= 1 && lane <= MS)
            v = (wave == 0) ? yh[PHYS(MS + lane - 1)] : yh[PHYS(MS + DIM - lane)];
        float s = v, q = v * v;
#pragma unroll
        for (int d = 1; d < 64; d <<= 1) {
            float ys = __shfl_up(s, d);
            float yq = __shfl_up(q, d);
            if (lane >= d) { s += ys; q += yq; }
        }
        if (lane <= MS) {
            if (wave == 0) { headS[lane] = s; headQ[lane] = q; }
            else           { tailS[lane] = s; tailQ[lane] = q; }
        }
    }
    __syncthreads();

    // yc chunk in registers: lane covers samples [32*lane, 32*lane+32)
    float ycr[32];
#pragma unroll
    for (int j = 0; j < 32; ++j) ycr[j] = yc[PHYS(32 * lane + j)];

    // sliding register window over yh: wave w handles lags [26w, 26w+26)
    const int c0 = 26 * wave;
    const int base0 = 32 * lane + c0;
    float wreg[32];
#pragma unroll
    for (int j = 0; j < 32; ++j) wreg[j] = yh[PHYS(base0 + j)];

    float cmax = -2.0f;
#pragma unroll
    for (int i = 0; i < 26; ++i) {
        float acc = 0.f;
#pragma unroll
        for (int j = 0; j < 32; ++j) acc += wreg[(i + j) & 31] * ycr[j];
#pragma unroll
        for (int d = 32; d; d >>= 1) acc += __shfl_down(acc, d);
        int c = c0 + i;
        if (lane == 0 && c < NWIN) {
            int off = c - MS;
            float sw, qw;
            if (off >= 0) { sw = S1 - headS[off]; qw = S2 - headQ[off]; }
            else          { sw = S1 - tailS[-off]; qw = S2 - tailQ[-off]; }
            float varw = qw - sw * sw * (1.0f / DIM);
            float corr = acc / sqrtf(varw * Syy);
            cmax = fmaxf(cmax, corr);
        }
        if (i < 25) wreg[i & 31] = yh[PHYS(base0 + 32 + i)];
    }
    if (lane == 0) red[wave] = cmax;
    __syncthreads();
    if (t == 0) {
        float m = fmaxf(fmaxf(red[0], red[1]), fmaxf(red[2], red[3]));
        sc[6] = (1.0f - m) / (1.0f + m);     // loss0
    }
    __syncthreads();   // Phase-P smem dead

    // ---------------- Phase F: packed complex FFT ---------------------------
    // z = yhat + i*x from registers
#pragma unroll
    for (int j = 0; j < 8; ++j) {
        A[8 * t + j] = make_float2(yhv[j], bv[j]);
    }
    __syncthreads();

    float2 *S = A, *D = Bb;
    // 5 radix-4 Stockham DIF stages (s = 1,4,16,64,256)
#pragma unroll
    for (int stage = 0; stage < 5; ++stage) {
        const int s = 1 << (2 * stage);
#pragma unroll
        for (int k = 0; k < 2; ++k) {
            int q = t + 256 * k;
            int u = q & ~(s - 1);
            float2 x0 = S[q];
            float2 x1 = S[q + 512];
            float2 x2 = S[q + 1024];
            float2 x3 = S[q + 1536];
            float t0r = x0.x + x2.x, t0i = x0.y + x2.y;
            float t1r = x0.x - x2.x, t1i = x0.y - x2.y;
            float t2r = x1.x + x3.x, t2i = x1.y + x3.y;
            float d3r = x1.x - x3.x, d3i = x1.y - x3.y;
            float t3r = d3i, t3i = -d3r;               // -i*(x1-x3)
            float2 w1 = TW[u];
            float w2r = w1.x * w1.x - w1.y * w1.y, w2i = 2.f * w1.x * w1.y;
            float w3r = w2r * w1.x - w2i * w1.y,  w3i = w2r * w1.y + w2i * w1.x;
            float y0r = t0r + t2r, y0i = t0i + t2i;
            float a1r = t1r + t3r, a1i = t1i + t3i;
            float y1r = a1r * w1.x - a1i * w1.y, y1i = a1r * w1.y + a1i * w1.x;
            float a2r = t0r - t2r, a2i = t0i - t2i;
            float y2r = a2r * w2r - a2i * w2i, y2i = a2r * w2i + a2i * w2r;
            float a3r = t1r - t3r, a3i = t1i - t3i;
            float y3r = a3r * w3r - a3i * w3i, y3i = a3r * w3i + a3i * w3r;
            int base = q + 3 * u;
            D[base]         = make_float2(y0r, y0i);
            D[base + s]     = make_float2(y1r, y1i);
            D[base + 2 * s] = make_float2(y2r, y2i);
            D[base + 3 * s] = make_float2(y3r, y3i);
        }
        __syncthreads();
        float2* tmp = S; S = D; D = tmp;
    }
    // final radix-2 stage (s = 1024, twiddle = 1)
#pragma unroll
    for (int k = 0; k < 4; ++k) {
        int b = t + 256 * k;
        float2 a = S[b], c = S[b + 1024];
        D[b]        = make_float2(a.x + c.x, a.y + c.y);
        D[b + 1024] = make_float2(a.x - c.x, a.y - c.y);
    }
    __syncthreads();
    // 6 swaps total -> final data in A; B region free for scans.

    // ---------------- Phase C: Hermitian unpack + chisq ---------------------
    const float MSC = 0.5f * (1.0f / 2048.0f);
    float h[4], sg[4];
#pragma unroll
    for (int j = 0; j < 4; ++j) {
        int m = 4 * t + j;
        if (m < NMASK) {
            int f = m + KMIN;
            int g = 2048 - f;
            float2 zf = A[f];
            float2 zg = A[g];
            float hre = zf.x + zg.x, him = zf.y - zg.y;
            float sre = zf.y + zg.y, sim = zg.x - zf.x;
            h[j]  = sqrtf(hre * hre + him * him) * MSC;
            sg[j] = sqrtf(sre * sre + sim * sim) * MSC;
        } else { h[j] = 0.f; sg[j] = 0.f; }
    }

    // ---- scan A: si = cumsum(4*|h|^2) ----
    float e0 = 4.f * h[0] * h[0];
    float e1 = e0 + 4.f * h[1] * h[1];
    float e2 = e1 + 4.f * h[2] * h[2];
    float e3 = e2 + 4.f * h[3] * h[3];
    float tot = e3;
    float inc = tot;
#pragma unroll
    for (int d = 1; d < 64; d <<= 1) {
        float y = __shfl_up(inc, d);
        if (lane >= d) inc += y;
    }
    if (lane == 63) wsum[wave] = inc;
    __syncthreads();
    float woff = 0.f;
    for (int w = 0; w < wave; ++w) woff += wsum[w];
    float pre = woff + inc - tot;
    siA[4 * t + 0] = pre + e0;
    siA[4 * t + 1] = pre + e1;
    siA[4 * t + 2] = pre + e2;
    siA[4 * t + 3] = pre + e3;
    __syncthreads();
    const float total = siA[NMASK - 1];

    // ---- scan B: si2 = cumsum(4*|h||s|/sqrt(total)) ----
    const float q = 1.0f / sqrtf(total);
    float g0 = 4.f * h[0] * sg[0] * q;
    float g1 = g0 + 4.f * h[1] * sg[1] * q;
    float g2 = g1 + 4.f * h[2] * sg[2] * q;
    float g3 = g2 + 4.f * h[3] * sg[3] * q;
    float tot2l = g3;
    float inc2 = tot2l;
#pragma unroll
    for (int d = 1; d < 64; d <<= 1) {
        float y = __shfl_up(inc2, d);
        if (lane >= d) inc2 += y;
    }
    if (lane == 63) wsum[wave] = inc2;
    __syncthreads();
    float woff2 = 0.f;
    for (int w = 0; w < wave; ++w) woff2 += wsum[w];
    float pre2 = woff2 + inc2 - tot2l;
    siB[4 * t + 0] = pre2 + g0;
    siB[4 * t + 1] = pre2 + g1;
    siB[4 * t + 2] = pre2 + g2;
    siB[4 * t + 3] = pre2 + g3;
    __syncthreads();
    const float total2 = siB[NMASK - 1];

    // ---- edges: searchsorted(siA, i/16*total, side='right'), clipped ----
    if (t < 17) {
        float bin = ((float)t * (1.0f / 16.0f)) * total;
        int lo = 0, hi = NMASK;
        while (lo < hi) {
            int mid = (lo + hi) >> 1;
            if (siA[mid] <= bin) lo = mid + 1; else hi = mid;
        }
        edges[t] = (lo < NMASK - 1) ? lo : (NMASK - 1);
    }
    __syncthreads();

    if (t < 16) {
        float snr = siB[edges[t + 1]] - siB[edges[t]];
        float d = snr - total2 * (1.0f / 16.0f);
        summ[t] = d * d;
    }
    __syncthreads();
    if (t == 0) {
        float ssum = 0.f;
        for (int i = 0; i < 16; ++i) ssum += summ[i];
        float chisq = 16.0f * ssum / 15.0f;
        float c3 = chisq * chisq * chisq;
        out[r] = sc[6] * powf(1.0f + c3, 1.0f / 6.0f);
    }
}

// ------------------------------------------------------------------
extern "C" void kernel_launch(void* const* d_in, const int* in_sizes, int n_in,
                              void* d_out, int out_size, void* d_ws, size_t ws_size,
                              hipStream_t stream) {
    const float* xhat = (const float*)d_in[0];
    const float* x    = (const float*)d_in[1];
    float* out = (float*)d_out;
    (void)d_ws; (void)ws_size;

    fused_mfl_kernel<<<ROWS, 256, 0, stream>>>(xhat, x, out);
}

// Round 4
// 73.223 us; speedup vs baseline: 1.4748x; 1.0629x over previous
//
#include <hip/hip_runtime.h>
#include <math.h>

#define ROWS 512
#define DIM 2048
#define MS 51            // MAX_SHIFT
#define NWIN 103         // 2*MS+1
#define KMIN 32          // HIGHPASS bins
#define NMASK 993        // 1025-32
#define PHYS(i) ((i) + ((i) >> 5))

// One block (512 threads, 8 waves) per row.
//  Phase P: center x_hat, shifted-Pearson max (sliding register window, 13 lags/wave)
//  Phase F: packed complex FFT z = yhat + i*x, radix-4 Stockham x5; final
//           radix-2 folded into the Hermitian unpack
//  Phase C: |H|,|S|; joint 993-elem scans; searchsorted; 16-bin chisq -> out[r]
__global__ __launch_bounds__(512) void fused_mfl_kernel(
    const float* __restrict__ xhat, const float* __restrict__ x,
    float* __restrict__ out)
{
    const int r = blockIdx.x;
    const int t = threadIdx.x;
    const int lane = t & 63;
    const int wave = t >> 6;          // 0..7
    const float* xh = xhat + (size_t)r * DIM;
    const float* xr = x + (size_t)r * DIM;

    // 36 KB arena, aliased across phases
    __shared__ float smem[9216];
    // Phase P carve
    float* yh    = smem;            // PHYS over [0,2150) -> 2217 floats
    float* yc    = smem + 2224;     // PHYS over [0,2048) -> 2111 floats
    float* headS = smem + 4352;     // 52
    float* headQ = smem + 4404;     // 52
    float* tailS = smem + 4456;     // 52
    float* tailQ = smem + 4508;     // 52 (ends 4560)
    // Phase F carve
    float2* A  = (float2*)smem;             // 2048 cplx  [0,4096) floats
    float2* Bb = (float2*)(smem + 4096);    // 2048 cplx  [4096,8192)
    float2* TW = (float2*)(smem + 8192);    // 512 cplx   [8192,9216)
    // Phase C carve (A float-region [0,2048) is free: data ends in Bb)
    float* siA  = smem;             // 1024
    float* siBr = smem + 1024;      // 1024 (unscaled scan B)

    __shared__ float red[32];
    __shared__ float sc[8];
    __shared__ int   edges[17];
    __shared__ float summ[16];
    __shared__ float wsA[8], wsB[8];

    // ---------------- load inputs (kept in registers across phases) --------
    float4 a4 = ((const float4*)xh)[t];
    float4 b4 = ((const float4*)xr)[t];
    float av[4] = {a4.x, a4.y, a4.z, a4.w};
    float bv[4] = {b4.x, b4.y, b4.z, b4.w};

    // twiddle table: TW[u] = exp(-i*pi*u/1024), u in [0,512)
    {
        float swv, cwv;
        sincosf((float)t * (-3.14159265358979323846f / 1024.0f), &swv, &cwv);
        TW[t] = make_float2(cwv, swv);
    }

    // ---------------- Phase P: center + shifted Pearson --------------------
    float mn = av[0], mx = av[0], sx = 0.f;
#pragma unroll
    for (int j = 0; j < 4; ++j) {
        mn = fminf(mn, av[j]); mx = fmaxf(mx, av[j]); sx += bv[j];
    }
#pragma unroll
    for (int d = 32; d; d >>= 1) {
        mn = fminf(mn, __shfl_down(mn, d));
        mx = fmaxf(mx, __shfl_down(mx, d));
        sx += __shfl_down(sx, d);
    }
    if (lane == 0) { red[wave] = mn; red[8 + wave] = mx; red[16 + wave] = sx; }
    __syncthreads();
    if (t == 0) {
        float m0 = red[0], m1 = red[8], s = red[16];
        for (int w = 1; w < 8; ++w) {
            m0 = fminf(m0, red[w]); m1 = fmaxf(m1, red[8 + w]); s += red[16 + w];
        }
        sc[0] = m0; sc[1] = m1; sc[2] = s * (1.0f / DIM);
    }
    __syncthreads();
    mn = sc[0]; mx = sc[1];
    const float mean = sc[2];
    const float scale = 2.0f / (mx - mn);

    float s1 = 0.f, s2 = 0.f, syy = 0.f;
    float yhv[4];
#pragma unroll
    for (int j = 0; j < 4; ++j) {
        float y = (av[j] - mn) * scale - 1.0f;
        float z = bv[j] - mean;
        yhv[j] = y;
        s1 += y; s2 += y * y; syy += z * z;
        int i = 4 * t + j;
        yh[PHYS(i + MS)] = y;
        yc[PHYS(i)] = z;
    }
    if (t < MS) { yh[PHYS(t)] = 0.f; yh[PHYS(t + MS + DIM)] = 0.f; }

#pragma unroll
    for (int d = 32; d; d >>= 1) {
        s1 += __shfl_down(s1, d); s2 += __shfl_down(s2, d); syy += __shfl_down(syy, d);
    }
    if (lane == 0) { red[wave] = s1; red[8 + wave] = s2; red[16 + wave] = syy; }
    __syncthreads();
    if (t == 0) {
        float p0 = 0.f, p1 = 0.f, p2 = 0.f;
        for (int w = 0; w < 8; ++w) { p0 += red[w]; p1 += red[8 + w]; p2 += red[16 + w]; }
        sc[3] = p0; sc[4] = p1; sc[5] = p2;
    }
    __syncthreads();
    const float S1 = sc[3], S2 = sc[4], Syy = sc[5];

    // head/tail exclusive prefix sums, wave-parallel (waves 0 and 1)
    if (wave < 2) {
        float v = 0.f;
        if (lane >= 1 && lane <= MS)
            v = (wave == 0) ? yh[PHYS(MS + lane - 1)] : yh[PHYS(MS + DIM - lane)];
        float s = v, q = v * v;
#pragma unroll
        for (int d = 1; d < 64; d <<= 1) {
            float ys = __shfl_up(s, d);
            float yq = __shfl_up(q, d);
            if (lane >= d) { s += ys; q += yq; }
        }
        if (lane <= MS) {
            if (wave == 0) { headS[lane] = s; headQ[lane] = q; }
            else           { tailS[lane] = s; tailQ[lane] = q; }
        }
    }
    __syncthreads();

    // yc chunk in registers: lane covers samples [32*lane, 32*lane+32)
    float ycr[32];
#pragma unroll
    for (int j = 0; j < 32; ++j) ycr[j] = yc[PHYS(32 * lane + j)];

    // sliding register window over yh: wave w handles lags [13w, 13w+13)
    const int c0 = 13 * wave;
    const int base0 = 32 * lane + c0;
    float wreg[32];
#pragma unroll
    for (int j = 0; j < 32; ++j) wreg[j] = yh[PHYS(base0 + j)];

    float cmax = -2.0f;
#pragma unroll
    for (int i = 0; i < 13; ++i) {
        float acc = 0.f;
#pragma unroll
        for (int j = 0; j < 32; ++j) acc += wreg[(i + j) & 31] * ycr[j];
#pragma unroll
        for (int d = 32; d; d >>= 1) acc += __shfl_down(acc, d);
        int c = c0 + i;
        if (lane == 0 && c < NWIN) {
            int off = c - MS;
            float sw, qw;
            if (off >= 0) { sw = S1 - headS[off]; qw = S2 - headQ[off]; }
            else          { sw = S1 - tailS[-off]; qw = S2 - tailQ[-off]; }
            float varw = qw - sw * sw * (1.0f / DIM);
            float corr = acc / sqrtf(varw * Syy);
            cmax = fmaxf(cmax, corr);
        }
        if (i < 12) wreg[i & 31] = yh[PHYS(base0 + 32 + i)];
    }
    if (lane == 0) red[wave] = cmax;
    __syncthreads();     // also: all Phase-P LDS reads complete
    if (t == 0) {
        float m = red[0];
        for (int w = 1; w < 8; ++w) m = fmaxf(m, red[w]);
        sc[6] = (1.0f - m) / (1.0f + m);     // loss0 (read only by t==0 later)
    }

    // ---------------- Phase F: packed complex FFT ---------------------------
    // z = yhat + i*x from registers
#pragma unroll
    for (int j = 0; j < 4; ++j) {
        A[4 * t + j] = make_float2(yhv[j], bv[j]);
    }
    __syncthreads();

    float2 *S = A, *D = Bb;
    // 5 radix-4 Stockham DIF stages (s = 1,4,16,64,256); 512 butterflies each
#pragma unroll
    for (int stage = 0; stage < 5; ++stage) {
        const int s = 1 << (2 * stage);
        const int q = t;
        const int u = q & ~(s - 1);
        float2 x0 = S[q];
        float2 x1 = S[q + 512];
        float2 x2 = S[q + 1024];
        float2 x3 = S[q + 1536];
        float t0r = x0.x + x2.x, t0i = x0.y + x2.y;
        float t1r = x0.x - x2.x, t1i = x0.y - x2.y;
        float t2r = x1.x + x3.x, t2i = x1.y + x3.y;
        float d3r = x1.x - x3.x, d3i = x1.y - x3.y;
        float t3r = d3i, t3i = -d3r;               // -i*(x1-x3)
        float2 w1 = TW[u];
        float w2r = w1.x * w1.x - w1.y * w1.y, w2i = 2.f * w1.x * w1.y;
        float w3r = w2r * w1.x - w2i * w1.y,  w3i = w2r * w1.y + w2i * w1.x;
        float y0r = t0r + t2r, y0i = t0i + t2i;
        float a1r = t1r + t3r, a1i = t1i + t3i;
        float y1r = a1r * w1.x - a1i * w1.y, y1i = a1r * w1.y + a1i * w1.x;
        float a2r = t0r - t2r, a2i = t0i - t2i;
        float y2r = a2r * w2r - a2i * w2i, y2i = a2r * w2i + a2i * w2r;
        float a3r = t1r - t3r, a3i = t1i - t3i;
        float y3r = a3r * w3r - a3i * w3i, y3i = a3r * w3i + a3i * w3r;
        int base = q + 3 * u;
        D[base]         = make_float2(y0r, y0i);
        D[base + s]     = make_float2(y1r, y1i);
        D[base + 2 * s] = make_float2(y2r, y2i);
        D[base + 3 * s] = make_float2(y3r, y3i);
        __syncthreads();
        float2* tmp = S; S = D; D = tmp;
    }
    // 5 swaps -> data in Bb (S points there). Final radix-2 folded into unpack.

    // ---------------- Phase C: Hermitian unpack + chisq ---------------------
    // Full-FFT bins: X[f] = S[f] + S[f+1024] (f<1024); X[1024] = S[0] - S[1024];
    //                X[g] = S[g-1024] - S[g] (g>=1024).
    const float MSC = 0.5f * (1.0f / 2048.0f);
    float h[2], sg[2];
#pragma unroll
    for (int j = 0; j < 2; ++j) {
        int m = 2 * t + j;
        if (m < NMASK) {
            int f = m + KMIN;                  // 32..1024
            float zfr, zfi;
            if (f < 1024) {
                float2 p = S[f], q2 = S[f + 1024];
                zfr = p.x + q2.x; zfi = p.y + q2.y;
            } else {
                float2 p = S[0], q2 = S[1024];
                zfr = p.x - q2.x; zfi = p.y - q2.y;
            }
            int g = 2048 - f;                  // 1024..2016
            float2 p2 = S[g - 1024], q3 = S[g];
            float zgr = p2.x - q3.x, zgi = p2.y - q3.y;
            float hre = zfr + zgr, him = zfi - zgi;
            float sre = zfi + zgi, sim = zgr - zfr;
            h[j]  = sqrtf(hre * hre + him * him) * MSC;
            sg[j] = sqrtf(sre * sre + sim * sim) * MSC;
        } else { h[j] = 0.f; sg[j] = 0.f; }
    }

    // ---- joint scans: E = cumsum(4|h|^2), G = cumsum(4|h||s|) (unscaled) ---
    float e0 = 4.f * h[0] * h[0];
    float e1 = e0 + 4.f * h[1] * h[1];
    float g0 = 4.f * h[0] * sg[0];
    float g1 = g0 + 4.f * h[1] * sg[1];
    float totE = e1, totG = g1;
    float incE = totE, incG = totG;
#pragma unroll
    for (int d = 1; d < 64; d <<= 1) {
        float yE = __shfl_up(incE, d);
        float yG = __shfl_up(incG, d);
        if (lane >= d) { incE += yE; incG += yG; }
    }
    if (lane == 63) { wsA[wave] = incE; wsB[wave] = incG; }
    __syncthreads();
    float offE = 0.f, offG = 0.f;
    for (int w = 0; w < wave; ++w) { offE += wsA[w]; offG += wsB[w]; }
    float preE = offE + incE - totE;
    float preG = offG + incG - totG;
    siA[2 * t]      = preE + e0;
    siA[2 * t + 1]  = preE + e1;
    siBr[2 * t]     = preG + g0;
    siBr[2 * t + 1] = preG + g1;
    __syncthreads();
    const float total  = siA[NMASK - 1];
    const float qf     = 1.0f / sqrtf(total);
    const float total2 = siBr[NMASK - 1] * qf;

    // ---- edges: searchsorted(siA, i/16*total, side='right'), clipped ----
    if (t < 17) {
        float bin = ((float)t * (1.0f / 16.0f)) * total;
        int lo = 0, hi = NMASK;
        while (lo < hi) {
            int mid = (lo + hi) >> 1;
            if (siA[mid] <= bin) lo = mid + 1; else hi = mid;
        }
        edges[t] = (lo < NMASK - 1) ? lo : (NMASK - 1);
    }
    __syncthreads();

    if (t < 16) {
        float snr = (siBr[edges[t + 1]] - siBr[edges[t]]) * qf;
        float d = snr - total2 * (1.0f / 16.0f);
        summ[t] = d * d;
    }
    __syncthreads();
    if (t == 0) {
        float ssum = 0.f;
        for (int i = 0; i < 16; ++i) ssum += summ[i];
        float chisq = 16.0f * ssum / 15.0f;
        float c3 = chisq * chisq * chisq;
        out[r] = sc[6] * powf(1.0f + c3, 1.0f / 6.0f);
    }
}

// ------------------------------------------------------------------
extern "C" void kernel_launch(void* const* d_in, const int* in_sizes, int n_in,
                              void* d_out, int out_size, void* d_ws, size_t ws_size,
                              hipStream_t stream) {
    const float* xhat = (const float*)d_in[0];
    const float* x    = (const float*)d_in[1];
    float* out = (float*)d_out;
    (void)d_ws; (void)ws_size;

    fused_mfl_kernel<<<ROWS, 512, 0, stream>>>(xhat, x, out);
}

// Round 5
// 69.947 us; speedup vs baseline: 1.5439x; 1.0468x over previous
//
#include <hip/hip_runtime.h>
#include <math.h>

#define ROWS 512
#define DIM 2048
#define MS 51            // MAX_SHIFT
#define NWIN 103         // 2*MS+1
#define KMIN 32          // HIGHPASS bins
#define NMASK 993        // 1025-32
#define PHYS(i) ((i) + ((i) >> 5))

// One block (512 threads, 8 waves) per row.
//  Phase P: fused 6-quantity stats reduce; center; shifted-Pearson via
//           register-sliding window -> partial matrix V[103][64] -> b128 reduce
//  Phase F: packed complex FFT z = yhat + i*x, radix-4 Stockham x5; final
//           radix-2 folded into the Hermitian unpack
//  Phase C: |H|,|S|; joint 993-elem scans; searchsorted; 16-bin chisq -> out[r]
__global__ __launch_bounds__(512) void fused_mfl_kernel(
    const float* __restrict__ xhat, const float* __restrict__ x,
    float* __restrict__ out)
{
    const int r = blockIdx.x;
    const int t = threadIdx.x;
    const int lane = t & 63;
    const int wave = t >> 6;          // 0..7
    const float* xh = xhat + (size_t)r * DIM;
    const float* xr = x + (size_t)r * DIM;

    // 64 KB arena, aliased across phases (grid-limited to 2 blocks/CU -> free)
    __shared__ float smem[16384];
    float* red6  = smem;              // [0,3072) stats partials (pre-yh)
    float* yh    = smem;              // [0,2217)  PHYS over [0,2150)
    float* yc    = smem + 2224;       // [2224,4335) PHYS over [0,2048)
    float* headS = smem + 4352;       // 52
    float* headQ = smem + 4404;       // 52
    float* tailS = smem + 4456;       // 52
    float* tailQ = smem + 4508;       // 52 (ends 4560)
    float* V     = smem + 9216;       // 103 rows x stride 68 -> [9216,16220)
    float* corrv = smem + 16220;      // 103 -> [16220,16323)
    float2* A  = (float2*)smem;             // 2048 cplx  [0,4096) floats
    float2* Bb = (float2*)(smem + 4096);    // 2048 cplx  [4096,8192)
    float2* TW = (float2*)(smem + 8192);    // 512 cplx   [8192,9216)
    float* siA  = smem;               // [0,1024)
    float* siBr = smem + 1024;        // [1024,2048)

    __shared__ float sc[8];
    __shared__ int   edges[17];
    __shared__ float summ[16];
    __shared__ float wsA[8], wsB[8];

    // ---------------- load inputs (kept in registers across phases) --------
    float4 a4 = ((const float4*)xh)[t];
    float4 b4 = ((const float4*)xr)[t];
    float av[4] = {a4.x, a4.y, a4.z, a4.w};
    float bv[4] = {b4.x, b4.y, b4.z, b4.w};

    // twiddle table: TW[u] = exp(-i*pi*u/1024), u in [0,512)
    {
        float swv, cwv;
        sincosf((float)t * (-3.14159265358979323846f / 1024.0f), &swv, &cwv);
        TW[t] = make_float2(cwv, swv);
    }

    // ---------------- fused 6-quantity stats reduction ----------------------
    {
        float mn4 = fminf(fminf(av[0], av[1]), fminf(av[2], av[3]));
        float mx4 = fmaxf(fmaxf(av[0], av[1]), fmaxf(av[2], av[3]));
        float sa = (av[0] + av[1]) + (av[2] + av[3]);
        float qa = (av[0]*av[0] + av[1]*av[1]) + (av[2]*av[2] + av[3]*av[3]);
        float sx = (bv[0] + bv[1]) + (bv[2] + bv[3]);
        float qx = (bv[0]*bv[0] + bv[1]*bv[1]) + (bv[2]*bv[2] + bv[3]*bv[3]);
        red6[t]        = mn4;
        red6[512 + t]  = mx4;
        red6[1024 + t] = sa;
        red6[1536 + t] = qa;
        red6[2048 + t] = sx;
        red6[2560 + t] = qx;
    }
    __syncthreads();                                   // B1
    if (wave == 0) {
        float4 u, v;
        u = ((const float4*)(red6       ))[2*lane]; v = ((const float4*)(red6       ))[2*lane+1];
        float pmn = fminf(fminf(fminf(u.x,u.y),fminf(u.z,u.w)),
                          fminf(fminf(v.x,v.y),fminf(v.z,v.w)));
        u = ((const float4*)(red6 +  512))[2*lane]; v = ((const float4*)(red6 +  512))[2*lane+1];
        float pmx = fmaxf(fmaxf(fmaxf(u.x,u.y),fmaxf(u.z,u.w)),
                          fmaxf(fmaxf(v.x,v.y),fmaxf(v.z,v.w)));
        u = ((const float4*)(red6 + 1024))[2*lane]; v = ((const float4*)(red6 + 1024))[2*lane+1];
        float psa = ((u.x+u.y)+(u.z+u.w)) + ((v.x+v.y)+(v.z+v.w));
        u = ((const float4*)(red6 + 1536))[2*lane]; v = ((const float4*)(red6 + 1536))[2*lane+1];
        float pqa = ((u.x+u.y)+(u.z+u.w)) + ((v.x+v.y)+(v.z+v.w));
        u = ((const float4*)(red6 + 2048))[2*lane]; v = ((const float4*)(red6 + 2048))[2*lane+1];
        float psx = ((u.x+u.y)+(u.z+u.w)) + ((v.x+v.y)+(v.z+v.w));
        u = ((const float4*)(red6 + 2560))[2*lane]; v = ((const float4*)(red6 + 2560))[2*lane+1];
        float pqx = ((u.x+u.y)+(u.z+u.w)) + ((v.x+v.y)+(v.z+v.w));
#pragma unroll
        for (int d = 32; d; d >>= 1) {
            pmn = fminf(pmn, __shfl_down(pmn, d));
            pmx = fmaxf(pmx, __shfl_down(pmx, d));
            psa += __shfl_down(psa, d);
            pqa += __shfl_down(pqa, d);
            psx += __shfl_down(psx, d);
            pqx += __shfl_down(pqx, d);
        }
        if (lane == 0) {
            float mn = pmn, mx = pmx;
            float scl = 2.0f / (mx - mn);
            float mean = psx * (1.0f / DIM);
            float Sm = psa - (float)DIM * mn;           // sum(a - mn)
            float S1 = scl * Sm - (float)DIM;
            float S2 = scl * scl * (pqa - 2.f * mn * psa + (float)DIM * mn * mn)
                     - 2.f * scl * Sm + (float)DIM;
            float Syy = pqx - (float)DIM * mean * mean;
            sc[0] = mn; sc[1] = scl; sc[2] = mean;
            sc[3] = S1; sc[4] = S2; sc[5] = Syy;
        }
    }
    __syncthreads();                                   // B2
    const float mnv = sc[0], scl = sc[1], mean = sc[2];
    const float S1 = sc[3], S2 = sc[4], Syy = sc[5];

    // ---------------- center + stage yh / yc --------------------------------
    float yhv[4];
#pragma unroll
    for (int j = 0; j < 4; ++j) {
        float y = (av[j] - mnv) * scl - 1.0f;
        float z = bv[j] - mean;
        yhv[j] = y;
        int i = 4 * t + j;
        yh[PHYS(i + MS)] = y;
        yc[PHYS(i)] = z;
    }
    if (t < MS) { yh[PHYS(t)] = 0.f; yh[PHYS(t + MS + DIM)] = 0.f; }
    __syncthreads();                                   // B3

    // head/tail exclusive prefix sums (waves 0,1)
    if (wave < 2) {
        float v = 0.f;
        if (lane >= 1 && lane <= MS)
            v = (wave == 0) ? yh[PHYS(MS + lane - 1)] : yh[PHYS(MS + DIM - lane)];
        float s = v, q = v * v;
#pragma unroll
        for (int d = 1; d < 64; d <<= 1) {
            float ys = __shfl_up(s, d);
            float yq = __shfl_up(q, d);
            if (lane >= d) { s += ys; q += yq; }
        }
        if (lane <= MS) {
            if (wave == 0) { headS[lane] = s; headQ[lane] = q; }
            else           { tailS[lane] = s; tailQ[lane] = q; }
        }
    }

    // yc chunk in registers: lane covers samples [32*lane, 32*lane+32)
    float ycr[32];
#pragma unroll
    for (int j = 0; j < 32; ++j) ycr[j] = yc[PHYS(32 * lane + j)];

    // sliding register window; wave w handles lags [13w, 13w+13)
    const int c0 = 13 * wave;
    const int base0 = 32 * lane + c0;
    float wreg[32];
#pragma unroll
    for (int j = 0; j < 32; ++j) wreg[j] = yh[PHYS(base0 + j)];

    float pacc[13];
#pragma unroll
    for (int i = 0; i < 13; ++i) {
        float acc = 0.f;
#pragma unroll
        for (int j = 0; j < 32; ++j) acc += wreg[(i + j) & 31] * ycr[j];
        pacc[i] = acc;
        if (i < 12) wreg[i & 31] = yh[PHYS(base0 + 32 + i)];
    }
#pragma unroll
    for (int i = 0; i < 13; ++i) {
        int c = c0 + i;
        if (c < NWIN) V[68 * c + lane] = pacc[i];
    }
    __syncthreads();                                   // B4

    // V-reduce: 4 threads per lag, b128 reads (stride-68 rows -> even spread)
    if (t < 4 * NWIN) {
        int c = t >> 2, k = t & 3;
        const float4* vp = (const float4*)(V + 68 * c + 16 * k);
        float4 u0 = vp[0], u1 = vp[1], u2 = vp[2], u3 = vp[3];
        float acc = ((u0.x+u0.y)+(u0.z+u0.w)) + ((u1.x+u1.y)+(u1.z+u1.w))
                  + ((u2.x+u2.y)+(u2.z+u2.w)) + ((u3.x+u3.y)+(u3.z+u3.w));
        acc += __shfl_down(acc, 1);
        acc += __shfl_down(acc, 2);
        if (k == 0) {
            int off = c - MS;
            float sw, qw;
            if (off >= 0) { sw = S1 - headS[off]; qw = S2 - headQ[off]; }
            else          { sw = S1 - tailS[-off]; qw = S2 - tailQ[-off]; }
            float varw = qw - sw * sw * (1.0f / DIM);
            corrv[c] = acc / sqrtf(varw * Syy);
        }
    }
    // FFT input (overwrites dead yh/yc region; disjoint from V/head/tail)
#pragma unroll
    for (int j = 0; j < 4; ++j) A[4 * t + j] = make_float2(yhv[j], bv[j]);
    __syncthreads();                                   // B5

    // corr max -> loss0 (wave 0, concurrent with other waves entering FFT)
    if (wave == 0) {
        float m = (lane < NWIN) ? corrv[lane] : -2.0f;
        if (lane + 64 < NWIN) m = fmaxf(m, corrv[lane + 64]);
#pragma unroll
        for (int d = 32; d; d >>= 1) m = fmaxf(m, __shfl_down(m, d));
        if (lane == 0) sc[6] = (1.0f - m) / (1.0f + m);
    }

    // ---------------- Phase F: packed complex FFT ---------------------------
    float2 *S = A, *D = Bb;
#pragma unroll
    for (int stage = 0; stage < 5; ++stage) {
        const int s = 1 << (2 * stage);
        const int q = t;
        const int u = q & ~(s - 1);
        float2 x0 = S[q];
        float2 x1 = S[q + 512];
        float2 x2 = S[q + 1024];
        float2 x3 = S[q + 1536];
        float t0r = x0.x + x2.x, t0i = x0.y + x2.y;
        float t1r = x0.x - x2.x, t1i = x0.y - x2.y;
        float t2r = x1.x + x3.x, t2i = x1.y + x3.y;
        float d3r = x1.x - x3.x, d3i = x1.y - x3.y;
        float t3r = d3i, t3i = -d3r;               // -i*(x1-x3)
        float2 w1 = TW[u];
        float w2r = w1.x * w1.x - w1.y * w1.y, w2i = 2.f * w1.x * w1.y;
        float w3r = w2r * w1.x - w2i * w1.y,  w3i = w2r * w1.y + w2i * w1.x;
        float y0r = t0r + t2r, y0i = t0i + t2i;
        float a1r = t1r + t3r, a1i = t1i + t3i;
        float y1r = a1r * w1.x - a1i * w1.y, y1i = a1r * w1.y + a1i * w1.x;
        float a2r = t0r - t2r, a2i = t0i - t2i;
        float y2r = a2r * w2r - a2i * w2i, y2i = a2r * w2i + a2i * w2r;
        float a3r = t1r - t3r, a3i = t1i - t3i;
        float y3r = a3r * w3r - a3i * w3i, y3i = a3r * w3i + a3i * w3r;
        int base = q + 3 * u;
        D[base]         = make_float2(y0r, y0i);
        D[base + s]     = make_float2(y1r, y1i);
        D[base + 2 * s] = make_float2(y2r, y2i);
        D[base + 3 * s] = make_float2(y3r, y3i);
        __syncthreads();                               // B6..B10
        float2* tmp = S; S = D; D = tmp;
    }
    // 5 swaps -> data in Bb (S points there). Final radix-2 folded into unpack.

    // ---------------- Phase C: Hermitian unpack + chisq ---------------------
    const float MSC = 0.5f * (1.0f / 2048.0f);
    float h[2], sg[2];
#pragma unroll
    for (int j = 0; j < 2; ++j) {
        int m = 2 * t + j;
        if (m < NMASK) {
            int f = m + KMIN;                  // 32..1024
            float zfr, zfi;
            if (f < 1024) {
                float2 p = S[f], q2 = S[f + 1024];
                zfr = p.x + q2.x; zfi = p.y + q2.y;
            } else {
                float2 p = S[0], q2 = S[1024];
                zfr = p.x - q2.x; zfi = p.y - q2.y;
            }
            int g = 2048 - f;                  // 1024..2016
            float2 p2 = S[g - 1024], q3 = S[g];
            float zgr = p2.x - q3.x, zgi = p2.y - q3.y;
            float hre = zfr + zgr, him = zfi - zgi;
            float sre = zfi + zgi, sim = zgr - zfr;
            h[j]  = sqrtf(hre * hre + him * him) * MSC;
            sg[j] = sqrtf(sre * sre + sim * sim) * MSC;
        } else { h[j] = 0.f; sg[j] = 0.f; }
    }

    // ---- joint scans: E = cumsum(4|h|^2), G = cumsum(4|h||s|) (unscaled) ---
    float e0 = 4.f * h[0] * h[0];
    float e1 = e0 + 4.f * h[1] * h[1];
    float g0 = 4.f * h[0] * sg[0];
    float g1 = g0 + 4.f * h[1] * sg[1];
    float totE = e1, totG = g1;
    float incE = totE, incG = totG;
#pragma unroll
    for (int d = 1; d < 64; d <<= 1) {
        float yE = __shfl_up(incE, d);
        float yG = __shfl_up(incG, d);
        if (lane >= d) { incE += yE; incG += yG; }
    }
    if (lane == 63) { wsA[wave] = incE; wsB[wave] = incG; }
    __syncthreads();                                   // B11
    float offE = 0.f, offG = 0.f;
    for (int w = 0; w < wave; ++w) { offE += wsA[w]; offG += wsB[w]; }
    float preE = offE + incE - totE;
    float preG = offG + incG - totG;
    siA[2 * t]      = preE + e0;
    siA[2 * t + 1]  = preE + e1;
    siBr[2 * t]     = preG + g0;
    siBr[2 * t + 1] = preG + g1;
    __syncthreads();                                   // B12
    const float total  = siA[NMASK - 1];
    const float qf     = 1.0f / sqrtf(total);
    const float total2 = siBr[NMASK - 1] * qf;

    // ---- edges: searchsorted(siA, i/16*total, side='right'), clipped ----
    if (t < 17) {
        float bin = ((float)t * (1.0f / 16.0f)) * total;
        int lo = 0, hi = NMASK;
        while (lo < hi) {
            int mid = (lo + hi) >> 1;
            if (siA[mid] <= bin) lo = mid + 1; else hi = mid;
        }
        edges[t] = (lo < NMASK - 1) ? lo : (NMASK - 1);
    }
    __syncthreads();                                   // B13

    if (t < 16) {
        float snr = (siBr[edges[t + 1]] - siBr[edges[t]]) * qf;
        float d = snr - total2 * (1.0f / 16.0f);
        summ[t] = d * d;
    }
    __syncthreads();                                   // B14
    if (t == 0) {
        float ssum = 0.f;
        for (int i = 0; i < 16; ++i) ssum += summ[i];
        float chisq = 16.0f * ssum / 15.0f;
        float c3 = chisq * chisq * chisq;
        out[r] = sc[6] * powf(1.0f + c3, 1.0f / 6.0f);
    }
}

// ------------------------------------------------------------------
extern "C" void kernel_launch(void* const* d_in, const int* in_sizes, int n_in,
                              void* d_out, int out_size, void* d_ws, size_t ws_size,
                              hipStream_t stream) {
    const float* xhat = (const float*)d_in[0];
    const float* x    = (const float*)d_in[1];
    float* out = (float*)d_out;
    (void)in_sizes; (void)n_in; (void)out_size; (void)d_ws; (void)ws_size;

    fused_mfl_kernel<<<ROWS, 512, 0, stream>>>(xhat, x, out);
}

// Round 6
// 68.426 us; speedup vs baseline: 1.5782x; 1.0222x over previous
//
#include <hip/hip_runtime.h>
#include <math.h>

#define ROWS 512
#define DIM 2048
#define MS 51            // MAX_SHIFT
#define NWIN 103         // 2*MS+1
#define KMIN 32          // HIGHPASS bins
#define NMASK 993        // 1025-32
#define INVS (1.0f/8192.0f)   // 1/(4*2048): P carried 4x scale, IFFT 1/N

// One block (512 threads, 8 waves) per row.
//  Stats:  fused 6-quantity reduce -> closed-form S1,S2,Syy,mean,scale
//  FFT1:   packed complex FFT z = yhat + i*x (radix-4 Stockham x5, final
//          radix-2 folded into unpack)
//  Unpack: |H|,|S| for chisq (registers) + P = 4*H*conj(S) -> conj(P) to LDS
//  FFT2:   forward FFT of conj(P)  => Re/8192 = circular xcorr(yh,yc);
//          interleaved with chisq scans/searchsorted/summ (LDS-disjoint)
//  Corr:   linear = circular - wrap (<=51 terms/lag); Pearson max -> loss
__global__ __launch_bounds__(512) void fused_mfl_kernel(
    const float* __restrict__ xhat, const float* __restrict__ x,
    float* __restrict__ out)
{
    const int r = blockIdx.x;
    const int t = threadIdx.x;
    const int lane = t & 63;
    const int wave = t >> 6;          // 0..7
    const float* xh = xhat + (size_t)r * DIM;
    const float* xr = x + (size_t)r * DIM;

    // ~46 KB arena
    __shared__ float smem[11780];
    float2* A  = (float2*)smem;             // 2048 cplx [0,4096)
    float2* Bb = (float2*)(smem + 4096);    // 2048 cplx [4096,8192)
    float2* TW = (float2*)(smem + 8192);    // 512 cplx  [8192,9216)
    float* red6  = smem;                    // [0,3072) pre-FFT alias of A
    float* siA   = smem + 9216;             // 1024
    float* siBr  = smem + 10240;            // 1024
    float* headS = smem + 11264;            // 52
    float* headQ = smem + 11316;            // 52
    float* tailS = smem + 11368;            // 52
    float* tailQ = smem + 11420;            // 52
    float* yhH   = smem + 11472;            // 51
    float* yhT   = smem + 11523;            // 51
    float* ycH   = smem + 11574;            // 51
    float* ycT   = smem + 11625;            // 51
    float* corrv = smem + 11676;            // 103

    __shared__ float sc[8];
    __shared__ int   edges[17];
    __shared__ float summ[16];
    __shared__ float wsA[8], wsB[8];

    // ---------------- load inputs ------------------------------------------
    float4 a4 = ((const float4*)xh)[t];
    float4 b4 = ((const float4*)xr)[t];
    float av[4] = {a4.x, a4.y, a4.z, a4.w};
    float bv[4] = {b4.x, b4.y, b4.z, b4.w};

    // twiddle: TW[u] = exp(-i*pi*u/1024)
    {
        float swv, cwv;
        sincosf((float)t * (-3.14159265358979323846f / 1024.0f), &swv, &cwv);
        TW[t] = make_float2(cwv, swv);
    }

    // radix-4 Stockham DIF stage (reads Sp, writes Dp); caller barriers.
    auto fft_stage = [&](const float2* Sp, float2* Dp, const int s) {
        const int q = t;
        const int u = q & ~(s - 1);
        float2 x0 = Sp[q];
        float2 x1 = Sp[q + 512];
        float2 x2 = Sp[q + 1024];
        float2 x3 = Sp[q + 1536];
        float t0r = x0.x + x2.x, t0i = x0.y + x2.y;
        float t1r = x0.x - x2.x, t1i = x0.y - x2.y;
        float t2r = x1.x + x3.x, t2i = x1.y + x3.y;
        float d3r = x1.x - x3.x, d3i = x1.y - x3.y;
        float t3r = d3i, t3i = -d3r;               // -i*(x1-x3)
        float2 w1 = TW[u];
        float w2r = w1.x * w1.x - w1.y * w1.y, w2i = 2.f * w1.x * w1.y;
        float w3r = w2r * w1.x - w2i * w1.y,  w3i = w2r * w1.y + w2i * w1.x;
        float y0r = t0r + t2r, y0i = t0i + t2i;
        float a1r = t1r + t3r, a1i = t1i + t3i;
        float y1r = a1r * w1.x - a1i * w1.y, y1i = a1r * w1.y + a1i * w1.x;
        float a2r = t0r - t2r, a2i = t0i - t2i;
        float y2r = a2r * w2r - a2i * w2i, y2i = a2r * w2i + a2i * w2r;
        float a3r = t1r - t3r, a3i = t1i - t3i;
        float y3r = a3r * w3r - a3i * w3i, y3i = a3r * w3i + a3i * w3r;
        int base = q + 3 * u;
        Dp[base]         = make_float2(y0r, y0i);
        Dp[base + s]     = make_float2(y1r, y1i);
        Dp[base + 2 * s] = make_float2(y2r, y2i);
        Dp[base + 3 * s] = make_float2(y3r, y3i);
    };

    // ---------------- fused 6-quantity stats reduction ----------------------
    {
        float mn4 = fminf(fminf(av[0], av[1]), fminf(av[2], av[3]));
        float mx4 = fmaxf(fmaxf(av[0], av[1]), fmaxf(av[2], av[3]));
        float sa = (av[0] + av[1]) + (av[2] + av[3]);
        float qa = (av[0]*av[0] + av[1]*av[1]) + (av[2]*av[2] + av[3]*av[3]);
        float sx = (bv[0] + bv[1]) + (bv[2] + bv[3]);
        float qx = (bv[0]*bv[0] + bv[1]*bv[1]) + (bv[2]*bv[2] + bv[3]*bv[3]);
        red6[t]        = mn4;
        red6[512 + t]  = mx4;
        red6[1024 + t] = sa;
        red6[1536 + t] = qa;
        red6[2048 + t] = sx;
        red6[2560 + t] = qx;
    }
    __syncthreads();                                   // B1
    if (wave == 0) {
        float4 u, v;
        u = ((const float4*)(red6       ))[2*lane]; v = ((const float4*)(red6       ))[2*lane+1];
        float pmn = fminf(fminf(fminf(u.x,u.y),fminf(u.z,u.w)),
                          fminf(fminf(v.x,v.y),fminf(v.z,v.w)));
        u = ((const float4*)(red6 +  512))[2*lane]; v = ((const float4*)(red6 +  512))[2*lane+1];
        float pmx = fmaxf(fmaxf(fmaxf(u.x,u.y),fmaxf(u.z,u.w)),
                          fmaxf(fmaxf(v.x,v.y),fmaxf(v.z,v.w)));
        u = ((const float4*)(red6 + 1024))[2*lane]; v = ((const float4*)(red6 + 1024))[2*lane+1];
        float psa = ((u.x+u.y)+(u.z+u.w)) + ((v.x+v.y)+(v.z+v.w));
        u = ((const float4*)(red6 + 1536))[2*lane]; v = ((const float4*)(red6 + 1536))[2*lane+1];
        float pqa = ((u.x+u.y)+(u.z+u.w)) + ((v.x+v.y)+(v.z+v.w));
        u = ((const float4*)(red6 + 2048))[2*lane]; v = ((const float4*)(red6 + 2048))[2*lane+1];
        float psx = ((u.x+u.y)+(u.z+u.w)) + ((v.x+v.y)+(v.z+v.w));
        u = ((const float4*)(red6 + 2560))[2*lane]; v = ((const float4*)(red6 + 2560))[2*lane+1];
        float pqx = ((u.x+u.y)+(u.z+u.w)) + ((v.x+v.y)+(v.z+v.w));
#pragma unroll
        for (int d = 32; d; d >>= 1) {
            pmn = fminf(pmn, __shfl_down(pmn, d));
            pmx = fmaxf(pmx, __shfl_down(pmx, d));
            psa += __shfl_down(psa, d);
            pqa += __shfl_down(pqa, d);
            psx += __shfl_down(psx, d);
            pqx += __shfl_down(pqx, d);
        }
        if (lane == 0) {
            float mn = pmn, mx = pmx;
            float scl = 2.0f / (mx - mn);
            float mean = psx * (1.0f / DIM);
            float Sm = psa - (float)DIM * mn;           // sum(a - mn)
            float S1v = scl * Sm - (float)DIM;
            float S2v = scl * scl * (pqa - 2.f * mn * psa + (float)DIM * mn * mn)
                      - 2.f * scl * Sm + (float)DIM;
            float Syyv = pqx - (float)DIM * mean * mean;
            sc[0] = mn; sc[1] = scl; sc[2] = mean;
            sc[3] = S1v; sc[4] = S2v; sc[5] = Syyv;
        }
    }
    __syncthreads();                                   // B2
    const float mnv = sc[0], scl = sc[1], mean = sc[2];
    const float S1 = sc[3], S2 = sc[4], Syy = sc[5];

    // ---------------- center + FFT input + head/tail staging ----------------
#pragma unroll
    for (int j = 0; j < 4; ++j) {
        int i = 4 * t + j;
        float y = (av[j] - mnv) * scl - 1.0f;
        float z = bv[j] - mean;
        A[i] = make_float2(y, bv[j]);       // z-pack: yhat + i*x (raw x)
        if (i < MS)        { yhH[i] = y;        ycH[i] = z; }
        if (i >= DIM - MS) { yhT[i - (DIM - MS)] = y; ycT[i - (DIM - MS)] = z; }
    }
    __syncthreads();                                   // B3

    // head/tail exclusive prefix sums of yh (waves 0,1); consumed post-B14
    if (wave < 2) {
        float v = 0.f;
        if (lane >= 1 && lane <= MS)
            v = (wave == 0) ? yhH[lane - 1] : yhT[MS - lane];
        float s = v, q = v * v;
#pragma unroll
        for (int d = 1; d < 64; d <<= 1) {
            float ys = __shfl_up(s, d);
            float yq = __shfl_up(q, d);
            if (lane >= d) { s += ys; q += yq; }
        }
        if (lane <= MS) {
            if (wave == 0) { headS[lane] = s; headQ[lane] = q; }
            else           { tailS[lane] = s; tailQ[lane] = q; }
        }
    }

    // ---------------- FFT1 (A -> ... -> Bb) --------------------------------
    fft_stage(A, Bb, 1);    __syncthreads();           // B4
    fft_stage(Bb, A, 4);    __syncthreads();           // B5
    fft_stage(A, Bb, 16);   __syncthreads();           // B6
    fft_stage(Bb, A, 64);   __syncthreads();           // B7
    fft_stage(A, Bb, 256);  __syncthreads();           // B8
    // folded final radix-2: X[f] = Bb[f]+Bb[f+1024] (f<1024), X[f]=Bb[f-1024]-Bb[f] else

    // ---------------- unpack: h/sg (regs) + conj(P) -> A --------------------
    const float MSC = 0.5f * (1.0f / 2048.0f);
    float h[2], sg[2];
#pragma unroll
    for (int j = 0; j < 2; ++j) {
        int m = 2 * t + j;
        if (m < NMASK) {
            int f = m + KMIN;                  // 32..1024
            float zfr, zfi;
            if (f < 1024) {
                float2 p = Bb[f], q2 = Bb[f + 1024];
                zfr = p.x + q2.x; zfi = p.y + q2.y;
            } else {
                float2 p = Bb[0], q2 = Bb[1024];
                zfr = p.x - q2.x; zfi = p.y - q2.y;
            }
            int g = 2048 - f;                  // 1024..2016
            float2 p2 = Bb[g - 1024], q3 = Bb[g];
            float zgr = p2.x - q3.x, zgi = p2.y - q3.y;
            float hre = zfr + zgr, him = zfi - zgi;    // 2*H[f]
            float sre = zfi + zgi, sim = zgr - zfr;    // 2*S[f]
            h[j]  = sqrtf(hre * hre + him * him) * MSC;
            sg[j] = sqrtf(sre * sre + sim * sim) * MSC;
            float pr = hre * sre + him * sim;          // 4*Re(H*conj(S))
            float pi = him * sre - hre * sim;          // 4*Im(H*conj(S))
            A[f] = make_float2(pr, -pi);               // conj(P)
            if (f < 1024) A[2048 - f] = make_float2(pr, pi);
        } else { h[j] = 0.f; sg[j] = 0.f; }
    }
    if (t < 32) {
        if (t == 0) A[0] = make_float2(0.f, 0.f);      // P[0]=0 (yc zero-mean)
        else {
            int f = t;                                  // 1..31
            float2 p = Bb[f], q2 = Bb[f + 1024];
            float zfr = p.x + q2.x, zfi = p.y + q2.y;
            float2 p2 = Bb[1024 - f], q3 = Bb[2048 - f];
            float zgr = p2.x - q3.x, zgi = p2.y - q3.y;
            float hre = zfr + zgr, him = zfi - zgi;
            float sre = zfi + zgi, sim = zgr - zfr;
            float pr = hre * sre + him * sim;
            float pi = him * sre - hre * sim;
            A[f] = make_float2(pr, -pi);
            A[2048 - f] = make_float2(pr, pi);
        }
    }
    __syncthreads();                                   // B9

    // ---------------- FFT2 (conj(P): A -> ... -> Bb), scans interleaved -----
    // interval 1: scan shfl + FFT2 s=1
    float e0 = 4.f * h[0] * h[0];
    float e1 = e0 + 4.f * h[1] * h[1];
    float g0 = 4.f * h[0] * sg[0];
    float g1 = g0 + 4.f * h[1] * sg[1];
    float totE = e1, totG = g1;
    float incE = totE, incG = totG;
#pragma unroll
    for (int d = 1; d < 64; d <<= 1) {
        float yE = __shfl_up(incE, d);
        float yG = __shfl_up(incG, d);
        if (lane >= d) { incE += yE; incG += yG; }
    }
    if (lane == 63) { wsA[wave] = incE; wsB[wave] = incG; }
    fft_stage(A, Bb, 1);
    __syncthreads();                                   // B10

    // interval 2: scan combine/store + FFT2 s=4
    {
        float offE = 0.f, offG = 0.f;
        for (int w = 0; w < wave; ++w) { offE += wsA[w]; offG += wsB[w]; }
        float preE = offE + incE - totE;
        float preG = offG + incG - totG;
        siA[2 * t]      = preE + e0;
        siA[2 * t + 1]  = preE + e1;
        siBr[2 * t]     = preG + g0;
        siBr[2 * t + 1] = preG + g1;
    }
    fft_stage(Bb, A, 4);
    __syncthreads();                                   // B11

    // interval 3: totals + edges search + FFT2 s=16
    const float total  = siA[NMASK - 1];
    const float qf     = 1.0f / sqrtf(total);
    const float total2 = siBr[NMASK - 1] * qf;
    if (t < 17) {
        float bin = ((float)t * (1.0f / 16.0f)) * total;
        int lo = 0, hi = NMASK;
        while (lo < hi) {
            int mid = (lo + hi) >> 1;
            if (siA[mid] <= bin) lo = mid + 1; else hi = mid;
        }
        edges[t] = (lo < NMASK - 1) ? lo : (NMASK - 1);
    }
    fft_stage(A, Bb, 16);
    __syncthreads();                                   // B12

    // interval 4: summ + FFT2 s=64
    if (t < 16) {
        float snr = (siBr[edges[t + 1]] - siBr[edges[t]]) * qf;
        float d = snr - total2 * (1.0f / 16.0f);
        summ[t] = d * d;
    }
    fft_stage(Bb, A, 64);
    __syncthreads();                                   // B13

    fft_stage(A, Bb, 256);
    __syncthreads();                                   // B14
    // circular xcorr: ccorr[s] = Re(fold(Bb)[s]) * INVS

    // ---------------- Pearson: wrap-correct + normalize ---------------------
    if (t < 4 * NWIN) {
        int c = t >> 2, k = t & 3;
        int off = c - MS;                     // -51..51
        float acc = 0.f;
        if (off > 0) {
            for (int j = k; j < off; j += 4) acc += yhH[j] * ycT[MS - off + j];
        } else if (off < 0) {
            for (int j = k; j < -off; j += 4) acc += yhT[MS + off + j] * ycH[j];
        }
        acc += __shfl_down(acc, 1);
        acc += __shfl_down(acc, 2);
        if (k == 0) {
            int sidx = (off >= 0) ? off : (2048 + off);
            float cc = (sidx < 1024) ? (Bb[sidx].x + Bb[sidx + 1024].x)
                                     : (Bb[sidx - 1024].x - Bb[sidx].x);
            float num = cc * INVS - acc;
            float sw, qw;
            if (off >= 0) { sw = S1 - headS[off];  qw = S2 - headQ[off]; }
            else          { sw = S1 - tailS[-off]; qw = S2 - tailQ[-off]; }
            float varw = qw - sw * sw * (1.0f / DIM);
            corrv[c] = num / sqrtf(varw * Syy);
        }
    }
    __syncthreads();                                   // B15

    if (wave == 0) {
        float m = (lane < NWIN) ? corrv[lane] : -2.0f;
        if (lane + 64 < NWIN) m = fmaxf(m, corrv[lane + 64]);
#pragma unroll
        for (int d = 32; d; d >>= 1) m = fmaxf(m, __shfl_down(m, d));
        if (lane == 0) {
            float loss0 = (1.0f - m) / (1.0f + m);
            float ssum = 0.f;
            for (int i = 0; i < 16; ++i) ssum += summ[i];
            float chisq = 16.0f * ssum / 15.0f;
            float c3 = chisq * chisq * chisq;
            out[r] = loss0 * powf(1.0f + c3, 1.0f / 6.0f);
        }
    }
}

// ------------------------------------------------------------------
extern "C" void kernel_launch(void* const* d_in, const int* in_sizes, int n_in,
                              void* d_out, int out_size, void* d_ws, size_t ws_size,
                              hipStream_t stream) {
    const float* xhat = (const float*)d_in[0];
    const float* x    = (const float*)d_in[1];
    float* out = (float*)d_out;
    (void)in_sizes; (void)n_in; (void)out_size; (void)d_ws; (void)ws_size;

    fused_mfl_kernel<<<ROWS, 512, 0, stream>>>(xhat, x, out);
}

// Round 7
// 67.725 us; speedup vs baseline: 1.5946x; 1.0103x over previous
//
#include <hip/hip_runtime.h>
#include <math.h>

#define ROWS 512
#define DIM 2048
#define MS 51            // MAX_SHIFT
#define NWIN 103         // 2*MS+1
#define KMIN 32          // HIGHPASS bins
#define NMASK 993        // 1025-32

// One block (512 threads, 8 waves) per row.
//  FFT1 on RAW z=a+i*x (stats reduce + prefix scans hidden in stages 1-2)
//  Unpack: e/g for chisq (scl applied to h), P=4*A*conj(X) Hermitian -> Pc
//  FFT2: 1024-pt packed Hermitian IFFT (waves 0-3) with Q-build fused in
//        stage 1  ||  chisq scans/search/summ (waves 4-7)
//  Wrap: linear corr = circ - wrap + affine/pad corrections; Pearson max
__global__ __launch_bounds__(512) void fused_mfl_kernel(
    const float* __restrict__ xhat, const float* __restrict__ x,
    float* __restrict__ out)
{
    const int r = blockIdx.x;
    const int t = threadIdx.x;
    const int lane = t & 63;
    const int wave = t >> 6;          // 0..7

    __shared__ float smem[12928];     // ~50.5 KB arena
    float2* A2  = (float2*)smem;                 // 2048 cplx [0,4096)
    float2* B2  = (float2*)(smem + 4096);        // 2048 cplx [4096,8192)
    float2* TW  = (float2*)(smem + 8192);        // 512 cplx  [8192,9216)
    float* eArr = smem + 9216;                   // 1024
    float* gArr = smem + 10240;                  // 1024
    float* red6 = smem + 9216;                   // 3072 (alias, dead by B2)
    float* ah   = smem + 12288;                  // 51 raw a head
    float* xhd  = smem + 12339;                  // 51 raw x head
    float* at_  = smem + 12390;                  // 51 raw a tail
    float* xt_  = smem + 12441;                  // 51 raw x tail
    float* Ah   = smem + 12492;                  // 52 prefix sums
    float* Aqh  = smem + 12544;
    float* Xh   = smem + 12596;
    float* At   = smem + 12648;
    float* Aqt  = smem + 12700;
    float* Xt   = smem + 12752;
    float* corrv= smem + 12804;                  // 103
    float* siA  = smem;                          // 1024 (alias A2, post-Pc)
    float* siBr = smem + 1024;                   // 1024

    __shared__ float sc[8];
    __shared__ int   edges[17];
    __shared__ float summ[16];
    __shared__ float wsA[4], wsB[4];

    const float* xhp = xhat + (size_t)r * DIM;
    const float* xrp = x    + (size_t)r * DIM;
    float4 a4 = ((const float4*)xhp)[t];
    float4 b4 = ((const float4*)xrp)[t];
    float av[4] = {a4.x, a4.y, a4.z, a4.w};
    float bv[4] = {b4.x, b4.y, b4.z, b4.w};

    {   // twiddle: TW[u] = exp(-i*pi*u/1024)
        float swv, cwv;
        sincosf((float)t * (-3.14159265358979323846f / 1024.0f), &swv, &cwv);
        TW[t] = make_float2(cwv, swv);
    }

    // stage RAW FFT input + head/tail raw samples + stats partials
#pragma unroll
    for (int j = 0; j < 4; ++j) {
        int i = 4 * t + j;
        A2[i] = make_float2(av[j], bv[j]);
        if (i < MS)        { ah[i] = av[j]; xhd[i] = bv[j]; }
        if (i >= DIM - MS) { at_[i-(DIM-MS)] = av[j]; xt_[i-(DIM-MS)] = bv[j]; }
    }
    {
        float mn4 = fminf(fminf(av[0],av[1]), fminf(av[2],av[3]));
        float mx4 = fmaxf(fmaxf(av[0],av[1]), fmaxf(av[2],av[3]));
        float sa = (av[0]+av[1])+(av[2]+av[3]);
        float qa = (av[0]*av[0]+av[1]*av[1])+(av[2]*av[2]+av[3]*av[3]);
        float sx = (bv[0]+bv[1])+(bv[2]+bv[3]);
        float qx = (bv[0]*bv[0]+bv[1]*bv[1])+(bv[2]*bv[2]+bv[3]*bv[3]);
        red6[t] = mn4; red6[512+t] = mx4; red6[1024+t] = sa;
        red6[1536+t] = qa; red6[2048+t] = sx; red6[2560+t] = qx;
    }
    __syncthreads();                                   // B1

    // 2048-pt radix-4 Stockham DIF stage (512 butterflies, all threads)
    auto fft2048 = [&](const float2* Sp, float2* Dp, const int s) {
        const int q = t;
        const int u = q & ~(s - 1);
        float2 x0 = Sp[q], x1 = Sp[q+512], x2 = Sp[q+1024], x3 = Sp[q+1536];
        float t0r=x0.x+x2.x, t0i=x0.y+x2.y;
        float t1r=x0.x-x2.x, t1i=x0.y-x2.y;
        float t2r=x1.x+x3.x, t2i=x1.y+x3.y;
        float d3r=x1.x-x3.x, d3i=x1.y-x3.y;
        float t3r=d3i, t3i=-d3r;
        float2 w1 = TW[u];
        float w2r=w1.x*w1.x-w1.y*w1.y, w2i=2.f*w1.x*w1.y;
        float w3r=w2r*w1.x-w2i*w1.y,  w3i=w2r*w1.y+w2i*w1.x;
        float y0r=t0r+t2r, y0i=t0i+t2i;
        float a1r=t1r+t3r, a1i=t1i+t3i;
        float y1r=a1r*w1.x-a1i*w1.y, y1i=a1r*w1.y+a1i*w1.x;
        float a2r=t0r-t2r, a2i=t0i-t2i;
        float y2r=a2r*w2r-a2i*w2i, y2i=a2r*w2i+a2i*w2r;
        float a3r=t1r-t3r, a3i=t1i-t3i;
        float y3r=a3r*w3r-a3i*w3i, y3i=a3r*w3i+a3i*w3r;
        int base = q + 3*u;
        Dp[base]       = make_float2(y0r,y0i);
        Dp[base+s]     = make_float2(y1r,y1i);
        Dp[base+2*s]   = make_float2(y2r,y2i);
        Dp[base+3*s]   = make_float2(y3r,y3i);
    };
    // 1024-pt stage (256 butterflies, t<256 only)
    auto fft1024 = [&](const float2* Sp, float2* Dp, const int s) {
        const int q = t;
        const int u = q & ~(s - 1);
        float2 x0 = Sp[q], x1 = Sp[q+256], x2 = Sp[q+512], x3 = Sp[q+768];
        float t0r=x0.x+x2.x, t0i=x0.y+x2.y;
        float t1r=x0.x-x2.x, t1i=x0.y-x2.y;
        float t2r=x1.x+x3.x, t2i=x1.y+x3.y;
        float d3r=x1.x-x3.x, d3i=x1.y-x3.y;
        float t3r=d3i, t3i=-d3r;
        float2 w1 = TW[2*u];
        float w2r=w1.x*w1.x-w1.y*w1.y, w2i=2.f*w1.x*w1.y;
        float w3r=w2r*w1.x-w2i*w1.y,  w3i=w2r*w1.y+w2i*w1.x;
        float y0r=t0r+t2r, y0i=t0i+t2i;
        float a1r=t1r+t3r, a1i=t1i+t3i;
        float y1r=a1r*w1.x-a1i*w1.y, y1i=a1r*w1.y+a1i*w1.x;
        float a2r=t0r-t2r, a2i=t0i-t2i;
        float y2r=a2r*w2r-a2i*w2i, y2i=a2r*w2i+a2i*w2r;
        float a3r=t1r-t3r, a3i=t1i-t3i;
        float y3r=a3r*w3r-a3i*w3i, y3i=a3r*w3i+a3i*w3r;
        int base = q + 3*u;
        Dp[base]       = make_float2(y0r,y0i);
        Dp[base+s]     = make_float2(y1r,y1i);
        Dp[base+2*s]   = make_float2(y2r,y2i);
        Dp[base+3*s]   = make_float2(y3r,y3i);
    };

    // FFT1 s=1  ||  stats reduce (wave 0)
    fft2048(A2, B2, 1);
    if (wave == 0) {
        float4 u, v;
        u=((const float4*)(red6     ))[2*lane]; v=((const float4*)(red6     ))[2*lane+1];
        float pmn=fminf(fminf(fminf(u.x,u.y),fminf(u.z,u.w)),fminf(fminf(v.x,v.y),fminf(v.z,v.w)));
        u=((const float4*)(red6+ 512))[2*lane]; v=((const float4*)(red6+ 512))[2*lane+1];
        float pmx=fmaxf(fmaxf(fmaxf(u.x,u.y),fmaxf(u.z,u.w)),fmaxf(fmaxf(v.x,v.y),fmaxf(v.z,v.w)));
        u=((const float4*)(red6+1024))[2*lane]; v=((const float4*)(red6+1024))[2*lane+1];
        float psa=((u.x+u.y)+(u.z+u.w))+((v.x+v.y)+(v.z+v.w));
        u=((const float4*)(red6+1536))[2*lane]; v=((const float4*)(red6+1536))[2*lane+1];
        float pqa=((u.x+u.y)+(u.z+u.w))+((v.x+v.y)+(v.z+v.w));
        u=((const float4*)(red6+2048))[2*lane]; v=((const float4*)(red6+2048))[2*lane+1];
        float psx=((u.x+u.y)+(u.z+u.w))+((v.x+v.y)+(v.z+v.w));
        u=((const float4*)(red6+2560))[2*lane]; v=((const float4*)(red6+2560))[2*lane+1];
        float pqx=((u.x+u.y)+(u.z+u.w))+((v.x+v.y)+(v.z+v.w));
#pragma unroll
        for (int d = 32; d; d >>= 1) {
            pmn=fminf(pmn,__shfl_down(pmn,d)); pmx=fmaxf(pmx,__shfl_down(pmx,d));
            psa+=__shfl_down(psa,d); pqa+=__shfl_down(pqa,d);
            psx+=__shfl_down(psx,d); pqx+=__shfl_down(pqx,d);
        }
        if (lane == 0) {
            float scl = 2.0f/(pmx - pmn);
            float Cc  = scl*pmn + 1.0f;          // y = scl*a - Cc
            float mean = psx * (1.0f/DIM);
            sc[0]=scl; sc[1]=Cc; sc[2]=mean; sc[3]=psa; sc[4]=pqa;
            sc[5]=pqx - (float)DIM*mean*mean;    // Szz
        }
    }
    __syncthreads();                                   // B2

    // FFT1 s=4  ||  head/tail prefix scans (waves 2,3)
    fft2048(B2, A2, 4);
    if (wave == 2) {
        float va=0.f, vq=0.f, vx=0.f;
        if (lane >= 1 && lane <= MS) { float aa=ah[lane-1]; va=aa; vq=aa*aa; vx=xhd[lane-1]; }
#pragma unroll
        for (int d = 1; d < 64; d <<= 1) {
            float ya=__shfl_up(va,d), yq=__shfl_up(vq,d), yx=__shfl_up(vx,d);
            if (lane >= d) { va+=ya; vq+=yq; vx+=yx; }
        }
        if (lane <= MS) { Ah[lane]=va; Aqh[lane]=vq; Xh[lane]=vx; }
    } else if (wave == 3) {
        float va=0.f, vq=0.f, vx=0.f;
        if (lane >= 1 && lane <= MS) { float aa=at_[MS-lane]; va=aa; vq=aa*aa; vx=xt_[MS-lane]; }
#pragma unroll
        for (int d = 1; d < 64; d <<= 1) {
            float ya=__shfl_up(va,d), yq=__shfl_up(vq,d), yx=__shfl_up(vx,d);
            if (lane >= d) { va+=ya; vq+=yq; vx+=yx; }
        }
        if (lane <= MS) { At[lane]=va; Aqt[lane]=vq; Xt[lane]=vx; }
    }
    __syncthreads();                                   // B3
    fft2048(A2, B2, 16);  __syncthreads();             // B4
    fft2048(B2, A2, 64);  __syncthreads();             // B5
    fft2048(A2, B2, 256); __syncthreads();             // B6
    // FFT1 result in B2 (final radix-2 folded into unpack)

    const float scl = sc[0], Cc = sc[1], mean = sc[2];
    const float Sa = sc[3], Qa = sc[4], Szz = sc[5];

    // ---- unpack: e/g -> LDS, Pc = conj(4*A*conj(X)) -> A2 ----
    const float MSC = 0.5f * (1.0f / 2048.0f);
#pragma unroll
    for (int j = 0; j < 2; ++j) {
        int m = 2 * t + j;
        float e = 0.f, g = 0.f;
        if (m < NMASK) {
            int f = m + KMIN;
            float zfr, zfi;
            if (f < 1024) { float2 p=B2[f], q2=B2[f+1024]; zfr=p.x+q2.x; zfi=p.y+q2.y; }
            else          { float2 p=B2[0], q2=B2[1024];   zfr=p.x-q2.x; zfi=p.y-q2.y; }
            int gi = 2048 - f;
            float2 p2 = B2[gi-1024], q3 = B2[gi];
            float zgr = p2.x - q3.x, zgi = p2.y - q3.y;
            float hre = zfr + zgr, him = zfi - zgi;    // 2*A[f]
            float sre = zfi + zgi, sim = zgr - zfr;    // 2*X[f]
            float hm = scl * sqrtf(hre*hre + him*him) * MSC;
            float sm = sqrtf(sre*sre + sim*sim) * MSC;
            e = 4.f*hm*hm; g = 4.f*hm*sm;
            float pr = hre*sre + him*sim;              // 4*Re(A*conj(X))
            float pi = him*sre - hre*sim;              // 4*Im
            A2[f] = make_float2(pr, -pi);
            if (f < 1024) A2[2048-f] = make_float2(pr, pi);
        }
        eArr[m] = e; gArr[m] = g;
    }
    if (t < 32) {
        if (t == 0) A2[0] = make_float2(0.f, 0.f);     // P[0]=0 (z zero-mean)
        else {
            int f = t;
            float2 p=B2[f], q2=B2[f+1024];
            float zfr=p.x+q2.x, zfi=p.y+q2.y;
            float2 p2=B2[1024-f], q3=B2[2048-f];
            float zgr=p2.x-q3.x, zgi=p2.y-q3.y;
            float hre=zfr+zgr, him=zfi-zgi;
            float sre=zfi+zgi, sim=zgr-zfr;
            float pr=hre*sre+him*sim, pi=him*sre-hre*sim;
            A2[f]=make_float2(pr,-pi);
            A2[2048-f]=make_float2(pr,pi);
        }
    }
    __syncthreads();                                   // B7

    float2* Qlo = B2;
    float2* Qhi = B2 + 1024;

    // scan locals persist across intervals (t>=256)
    float se0=0,se1=0,se2=0,se3=0, sg0=0,sg1=0,sg2=0,sg3=0;
    float incE=0, incG=0, totE=0, totG=0;

    // FFT2 s=1 with fused Q-build (t<256)  ||  scan-local (t>=256)
    if (t < 256) {
        const int q = t;
        float2 wA = TW[q], wB = TW[q+256];
        auto mkQ = [&](int k, float2 w, int ni) -> float2 {
            float2 Pa = A2[k], Pb = A2[k+1024];
            float D1r = Pa.x+Pb.x, D1i = Pa.y+Pb.y;
            float D2r = Pa.x-Pb.x, D2i = Pa.y-Pb.y;
            float Er = D2r*w.x - D2i*w.y;
            float Ei = D2r*w.y + D2i*w.x;
            if (ni) return make_float2(D1r - Er, D1i - Ei);   // tw = -i*w
            return make_float2(D1r + Ei, D1i - Er);           // D1 - i*E
        };
        float2 x0 = mkQ(q,     wA, 0);
        float2 x1 = mkQ(q+256, wB, 0);
        float2 x2 = mkQ(q+512, wA, 1);
        float2 x3 = mkQ(q+768, wB, 1);
        float t0r=x0.x+x2.x, t0i=x0.y+x2.y;
        float t1r=x0.x-x2.x, t1i=x0.y-x2.y;
        float t2r=x1.x+x3.x, t2i=x1.y+x3.y;
        float d3r=x1.x-x3.x, d3i=x1.y-x3.y;
        float t3r=d3i, t3i=-d3r;
        float2 w1 = TW[2*q];
        float w2r=w1.x*w1.x-w1.y*w1.y, w2i=2.f*w1.x*w1.y;
        float w3r=w2r*w1.x-w2i*w1.y,  w3i=w2r*w1.y+w2i*w1.x;
        float y0r=t0r+t2r, y0i=t0i+t2i;
        float a1r=t1r+t3r, a1i=t1i+t3i;
        float y1r=a1r*w1.x-a1i*w1.y, y1i=a1r*w1.y+a1i*w1.x;
        float a2r=t0r-t2r, a2i=t0i-t2i;
        float y2r=a2r*w2r-a2i*w2i, y2i=a2r*w2i+a2i*w2r;
        float a3r=t1r-t3r, a3i=t1i-t3i;
        float y3r=a3r*w3r-a3i*w3i, y3i=a3r*w3i+a3i*w3r;
        Qlo[4*q]   = make_float2(y0r,y0i);
        Qlo[4*q+1] = make_float2(y1r,y1i);
        Qlo[4*q+2] = make_float2(y2r,y2i);
        Qlo[4*q+3] = make_float2(y3r,y3i);
    } else {
        int tt = t - 256;
        float4 e4 = ((const float4*)eArr)[tt];
        float4 g4 = ((const float4*)gArr)[tt];
        se0=e4.x; se1=se0+e4.y; se2=se1+e4.z; se3=se2+e4.w;
        sg0=g4.x; sg1=sg0+g4.y; sg2=sg1+g4.z; sg3=sg2+g4.w;
        totE=se3; totG=sg3; incE=totE; incG=totG;
#pragma unroll
        for (int d = 1; d < 64; d <<= 1) {
            float yE=__shfl_up(incE,d), yG=__shfl_up(incG,d);
            if (lane >= d) { incE+=yE; incG+=yG; }
        }
        if (lane == 63) { wsA[wave-4]=incE; wsB[wave-4]=incG; }
    }
    __syncthreads();                                   // B8

    // FFT2 s=4  ||  scan writeback
    if (t < 256) { fft1024(Qlo, Qhi, 4); }
    else {
        int tt = t - 256, w4 = wave - 4;
        float offE=0.f, offG=0.f;
        for (int w = 0; w < w4; ++w) { offE+=wsA[w]; offG+=wsB[w]; }
        float preE = offE + incE - totE;
        float preG = offG + incG - totG;
        ((float4*)siA)[tt]  = make_float4(preE+se0, preE+se1, preE+se2, preE+se3);
        ((float4*)siBr)[tt] = make_float4(preG+sg0, preG+sg1, preG+sg2, preG+sg3);
    }
    __syncthreads();                                   // B9

    // FFT2 s=16  ||  searchsorted
    if (t < 256) { fft1024(Qhi, Qlo, 16); }
    else if (t < 256 + 17) {
        int tl = t - 256;
        float total = siA[NMASK-1];
        float bin = ((float)tl * (1.0f/16.0f)) * total;
        int lo = 0, hi = NMASK;
        while (lo < hi) { int mid=(lo+hi)>>1; if (siA[mid] <= bin) lo=mid+1; else hi=mid; }
        edges[tl] = (lo < NMASK-1) ? lo : (NMASK-1);
    }
    __syncthreads();                                   // B10

    // FFT2 s=64  ||  summ
    if (t < 256) { fft1024(Qlo, Qhi, 64); }
    else if (t < 256 + 16) {
        int tl = t - 256;
        float total = siA[NMASK-1];
        float qf = 1.0f / sqrtf(total);
        float total2 = siBr[NMASK-1] * qf;
        float snr = (siBr[edges[tl+1]] - siBr[edges[tl]]) * qf;
        float d = snr - total2 * (1.0f/16.0f);
        summ[tl] = d * d;
    }
    __syncthreads();                                   // B11

    if (t < 256) { fft1024(Qhi, Qlo, 256); }
    __syncthreads();                                   // B12
    // F in Qlo; circ[2n]=Re(F[n])/8192, circ[2n+1]=-Im(F[n])/8192

    // ---- wrap-correct + affine Pearson ----
    if (t < 4 * NWIN) {
        int c = t >> 2, k = t & 3;
        int off = c - MS;
        float acc = 0.f;
        if (off > 0) {
            for (int j = k; j < off; j += 4) acc += ah[j] * (xt_[MS-off+j] - mean);
        } else if (off < 0) {
            int o = -off;
            for (int j = k; j < o; j += 4) acc += at_[MS-o+j] * (xhd[j] - mean);
        }
        acc += __shfl_down(acc, 1);
        acc += __shfl_down(acc, 2);
        if (k == 0) {
            int sidx = (off >= 0) ? off : (2048 + off);
            float2 Fv = Qlo[sidx >> 1];
            float val = (sidx & 1) ? -Fv.y : Fv.x;
            float circ = val * (1.0f/8192.0f);
            float Sin_a, Sin_q, Zex, nin;
            if (off >= 0) {
                Sin_a = Sa - Ah[off]; Sin_q = Qa - Aqh[off];
                Zex = Xt[off] - (float)off * mean; nin = 2048.0f - (float)off;
            } else {
                int o = -off;
                Sin_a = Sa - At[o]; Sin_q = Qa - Aqt[o];
                Zex = Xh[o] - (float)o * mean; nin = 2048.0f - (float)o;
            }
            float num = scl * (circ - acc) + Cc * Zex;
            float Sw  = scl * Sin_a - Cc * nin;
            float Sw2 = scl*scl*Sin_q - 2.f*scl*Cc*Sin_a + Cc*Cc*nin;
            float varw = Sw2 - Sw * Sw * (1.0f/2048.0f);
            corrv[c] = num / sqrtf(varw * Szz);
        }
    }
    __syncthreads();                                   // B13

    if (wave == 0) {
        float m = corrv[lane];
        if (lane + 64 < NWIN) m = fmaxf(m, corrv[lane + 64]);
#pragma unroll
        for (int d = 32; d; d >>= 1) m = fmaxf(m, __shfl_down(m, d));
        if (lane == 0) {
            float loss0 = (1.0f - m) / (1.0f + m);
            float ss = 0.f;
            for (int i = 0; i < 16; ++i) ss += summ[i];
            float chisq = 16.0f * ss / 15.0f;
            float c3 = chisq * chisq * chisq;
            out[r] = loss0 * powf(1.0f + c3, 1.0f/6.0f);
        }
    }
}

// ------------------------------------------------------------------
extern "C" void kernel_launch(void* const* d_in, const int* in_sizes, int n_in,
                              void* d_out, int out_size, void* d_ws, size_t ws_size,
                              hipStream_t stream) {
    const float* xhat = (const float*)d_in[0];
    const float* x    = (const float*)d_in[1];
    float* out = (float*)d_out;
    (void)in_sizes; (void)n_in; (void)out_size; (void)d_ws; (void)ws_size;

    fused_mfl_kernel<<<ROWS, 512, 0, stream>>>(xhat, x, out);
}

// Round 8
// 67.229 us; speedup vs baseline: 1.6063x; 1.0074x over previous
//
#include <hip/hip_runtime.h>
#include <math.h>

#define ROWS 512
#define DIM 2048
#define MS 51            // MAX_SHIFT
#define NWIN 103         // 2*MS+1
#define KMIN 32          // HIGHPASS bins
#define NMASK 993        // 1025-32

// One block (512 threads, 8 waves) per row. 10 barriers / 11 intervals.
//  I0: strided load + stats partials + head/tail stage + FFT1 s=1 from regs
//  I1: FFT1 s=4 || stats reduce (w0) || head/tail prefix scans (w2,w3)
//  I2-I4: FFT1 s=16,64,256
//  I5: fused unpack+Q-build+FFT2 s=1 (w0-3) || e/g compute + scan shfl (w4-7)
//  I6: FFT2 s=4 || scan writeback;  I7: s=16 || searchsorted
//  I8: s=64 || summ + wrap edge-sums;  I9: wrap (final butterfly inline)
//  I10: max reduce -> out
__global__ __launch_bounds__(512) void fused_mfl_kernel(
    const float* __restrict__ xhat, const float* __restrict__ x,
    float* __restrict__ out)
{
    const int r = blockIdx.x;
    const int t = threadIdx.x;
    const int lane = t & 63;
    const int wave = t >> 6;          // 0..7

    __shared__ float smem[13056];     // 51 KB arena
    float2* A2  = (float2*)smem;                 // 2048 cplx [0,4096)
    float2* B2  = (float2*)(smem + 4096);        // 2048 cplx [4096,8192)
    float2* TW  = (float2*)(smem + 8192);        // 512 cplx  [8192,9216)
    float2* Qlo = (float2*)smem;                 // 1024 cplx [0,2048)
    float2* Qhi = (float2*)smem + 1024;          // 1024 cplx [2048,4096)
    float* siA  = smem + 4096;                   // 1024 (B2 region, post-I5)
    float* siBr = smem + 5120;                   // 1024
    float* red6 = smem + 9216;                   // 3072 (dead after I1)
    float* ah   = smem + 12288;                  // 51 raw a head
    float* xhd  = smem + 12339;                  // 51 raw x head
    float* at_  = smem + 12390;                  // 51 raw a tail
    float* xt_  = smem + 12441;                  // 51 raw x tail
    float* Ah   = smem + 12492;                  // 52 prefix sums
    float* Aqh  = smem + 12544;
    float* Xh   = smem + 12596;
    float* At   = smem + 12648;
    float* Aqt  = smem + 12700;
    float* Xt   = smem + 12752;
    float* corrv= smem + 12804;                  // 103
    float* accv = smem + 12907;                  // 103 wrap edge-sums

    __shared__ float sc[8];
    __shared__ int   edges[17];
    __shared__ float summ[16];
    __shared__ float wsA[4], wsB[4];

    const float* xhp = xhat + (size_t)r * DIM;
    const float* xrp = x    + (size_t)r * DIM;
    // strided load: thread t holds samples {t, t+512, t+1024, t+1536}
    float av[4] = {xhp[t], xhp[t+512], xhp[t+1024], xhp[t+1536]};
    float bv[4] = {xrp[t], xrp[t+512], xrp[t+1024], xrp[t+1536]};

    // twiddle: TW[u] = exp(-i*pi*u/1024); this thread's s=1 twiddle = TW[t]
    float swv, cwv;
    sincosf((float)t * (-3.14159265358979323846f / 1024.0f), &swv, &cwv);
    TW[t] = make_float2(cwv, swv);

    // ---- I0: stats partials + head/tail + FFT1 s=1 from registers ----------
    {
        float mn4 = fminf(fminf(av[0],av[1]), fminf(av[2],av[3]));
        float mx4 = fmaxf(fmaxf(av[0],av[1]), fmaxf(av[2],av[3]));
        float sa = (av[0]+av[1])+(av[2]+av[3]);
        float qa = (av[0]*av[0]+av[1]*av[1])+(av[2]*av[2]+av[3]*av[3]);
        float sx = (bv[0]+bv[1])+(bv[2]+bv[3]);
        float qx = (bv[0]*bv[0]+bv[1]*bv[1])+(bv[2]*bv[2]+bv[3]*bv[3]);
        red6[t] = mn4; red6[512+t] = mx4; red6[1024+t] = sa;
        red6[1536+t] = qa; red6[2048+t] = sx; red6[2560+t] = qx;
    }
    if (t < MS)   { ah[t] = av[0];      xhd[t] = bv[0]; }
    if (t >= 461) { at_[t-461] = av[3]; xt_[t-461] = bv[3]; }  // samples 1997..2047
    {
        // radix-4 butterfly, s=1, u=q=t, w1 = (cwv,swv) local
        float t0r=av[0]+av[2], t0i=bv[0]+bv[2];
        float t1r=av[0]-av[2], t1i=bv[0]-bv[2];
        float t2r=av[1]+av[3], t2i=bv[1]+bv[3];
        float d3r=av[1]-av[3], d3i=bv[1]-bv[3];
        float t3r=d3i, t3i=-d3r;
        float w1r=cwv, w1i=swv;
        float w2r=w1r*w1r-w1i*w1i, w2i=2.f*w1r*w1i;
        float w3r=w2r*w1r-w2i*w1i, w3i=w2r*w1i+w2i*w1r;
        float y0r=t0r+t2r, y0i=t0i+t2i;
        float a1r=t1r+t3r, a1i=t1i+t3i;
        float y1r=a1r*w1r-a1i*w1i, y1i=a1r*w1i+a1i*w1r;
        float a2r=t0r-t2r, a2i=t0i-t2i;
        float y2r=a2r*w2r-a2i*w2i, y2i=a2r*w2i+a2i*w2r;
        float a3r=t1r-t3r, a3i=t1i-t3i;
        float y3r=a3r*w3r-a3i*w3i, y3i=a3r*w3i+a3i*w3r;
        B2[4*t]   = make_float2(y0r,y0i);
        B2[4*t+1] = make_float2(y1r,y1i);
        B2[4*t+2] = make_float2(y2r,y2i);
        B2[4*t+3] = make_float2(y3r,y3i);
    }
    __syncthreads();                                   // B1

    // 2048-pt radix-4 Stockham DIF stage
    auto fft2048 = [&](const float2* Sp, float2* Dp, const int s) {
        const int q = t;
        const int u = q & ~(s - 1);
        float2 x0 = Sp[q], x1 = Sp[q+512], x2 = Sp[q+1024], x3 = Sp[q+1536];
        float t0r=x0.x+x2.x, t0i=x0.y+x2.y;
        float t1r=x0.x-x2.x, t1i=x0.y-x2.y;
        float t2r=x1.x+x3.x, t2i=x1.y+x3.y;
        float d3r=x1.x-x3.x, d3i=x1.y-x3.y;
        float t3r=d3i, t3i=-d3r;
        float2 w1 = TW[u];
        float w2r=w1.x*w1.x-w1.y*w1.y, w2i=2.f*w1.x*w1.y;
        float w3r=w2r*w1.x-w2i*w1.y,  w3i=w2r*w1.y+w2i*w1.x;
        float y0r=t0r+t2r, y0i=t0i+t2i;
        float a1r=t1r+t3r, a1i=t1i+t3i;
        float y1r=a1r*w1.x-a1i*w1.y, y1i=a1r*w1.y+a1i*w1.x;
        float a2r=t0r-t2r, a2i=t0i-t2i;
        float y2r=a2r*w2r-a2i*w2i, y2i=a2r*w2i+a2i*w2r;
        float a3r=t1r-t3r, a3i=t1i-t3i;
        float y3r=a3r*w3r-a3i*w3i, y3i=a3r*w3i+a3i*w3r;
        int base = q + 3*u;
        Dp[base]     = make_float2(y0r,y0i);
        Dp[base+s]   = make_float2(y1r,y1i);
        Dp[base+2*s] = make_float2(y2r,y2i);
        Dp[base+3*s] = make_float2(y3r,y3i);
    };
    // 1024-pt stage (t<256 only)
    auto fft1024 = [&](const float2* Sp, float2* Dp, const int s) {
        const int q = t;
        const int u = q & ~(s - 1);
        float2 x0 = Sp[q], x1 = Sp[q+256], x2 = Sp[q+512], x3 = Sp[q+768];
        float t0r=x0.x+x2.x, t0i=x0.y+x2.y;
        float t1r=x0.x-x2.x, t1i=x0.y-x2.y;
        float t2r=x1.x+x3.x, t2i=x1.y+x3.y;
        float d3r=x1.x-x3.x, d3i=x1.y-x3.y;
        float t3r=d3i, t3i=-d3r;
        float2 w1 = TW[2*u];
        float w2r=w1.x*w1.x-w1.y*w1.y, w2i=2.f*w1.x*w1.y;
        float w3r=w2r*w1.x-w2i*w1.y,  w3i=w2r*w1.y+w2i*w1.x;
        float y0r=t0r+t2r, y0i=t0i+t2i;
        float a1r=t1r+t3r, a1i=t1i+t3i;
        float y1r=a1r*w1.x-a1i*w1.y, y1i=a1r*w1.y+a1i*w1.x;
        float a2r=t0r-t2r, a2i=t0i-t2i;
        float y2r=a2r*w2r-a2i*w2i, y2i=a2r*w2i+a2i*w2r;
        float a3r=t1r-t3r, a3i=t1i-t3i;
        float y3r=a3r*w3r-a3i*w3i, y3i=a3r*w3i+a3i*w3r;
        int base = q + 3*u;
        Dp[base]     = make_float2(y0r,y0i);
        Dp[base+s]   = make_float2(y1r,y1i);
        Dp[base+2*s] = make_float2(y2r,y2i);
        Dp[base+3*s] = make_float2(y3r,y3i);
    };

    // ---- I1: FFT1 s=4 || stats reduce (w0) || prefix scans (w2,w3) ---------
    fft2048(B2, A2, 4);
    if (wave == 0) {
        float4 u, v;
        u=((const float4*)(red6     ))[2*lane]; v=((const float4*)(red6     ))[2*lane+1];
        float pmn=fminf(fminf(fminf(u.x,u.y),fminf(u.z,u.w)),fminf(fminf(v.x,v.y),fminf(v.z,v.w)));
        u=((const float4*)(red6+ 512))[2*lane]; v=((const float4*)(red6+ 512))[2*lane+1];
        float pmx=fmaxf(fmaxf(fmaxf(u.x,u.y),fmaxf(u.z,u.w)),fmaxf(fmaxf(v.x,v.y),fmaxf(v.z,v.w)));
        u=((const float4*)(red6+1024))[2*lane]; v=((const float4*)(red6+1024))[2*lane+1];
        float psa=((u.x+u.y)+(u.z+u.w))+((v.x+v.y)+(v.z+v.w));
        u=((const float4*)(red6+1536))[2*lane]; v=((const float4*)(red6+1536))[2*lane+1];
        float pqa=((u.x+u.y)+(u.z+u.w))+((v.x+v.y)+(v.z+v.w));
        u=((const float4*)(red6+2048))[2*lane]; v=((const float4*)(red6+2048))[2*lane+1];
        float psx=((u.x+u.y)+(u.z+u.w))+((v.x+v.y)+(v.z+v.w));
        u=((const float4*)(red6+2560))[2*lane]; v=((const float4*)(red6+2560))[2*lane+1];
        float pqx=((u.x+u.y)+(u.z+u.w))+((v.x+v.y)+(v.z+v.w));
#pragma unroll
        for (int d = 32; d; d >>= 1) {
            pmn=fminf(pmn,__shfl_down(pmn,d)); pmx=fmaxf(pmx,__shfl_down(pmx,d));
            psa+=__shfl_down(psa,d); pqa+=__shfl_down(pqa,d);
            psx+=__shfl_down(psx,d); pqx+=__shfl_down(pqx,d);
        }
        if (lane == 0) {
            float scl = 2.0f/(pmx - pmn);
            float Cc  = scl*pmn + 1.0f;          // y = scl*a - Cc
            float mean = psx * (1.0f/DIM);
            sc[0]=scl; sc[1]=Cc; sc[2]=mean; sc[3]=psa; sc[4]=pqa;
            sc[5]=pqx - (float)DIM*mean*mean;    // Szz
        }
    } else if (wave == 2) {
        float va=0.f, vq=0.f, vx=0.f;
        if (lane >= 1 && lane <= MS) { float aa=ah[lane-1]; va=aa; vq=aa*aa; vx=xhd[lane-1]; }
#pragma unroll
        for (int d = 1; d < 64; d <<= 1) {
            float ya=__shfl_up(va,d), yq=__shfl_up(vq,d), yx=__shfl_up(vx,d);
            if (lane >= d) { va+=ya; vq+=yq; vx+=yx; }
        }
        if (lane <= MS) { Ah[lane]=va; Aqh[lane]=vq; Xh[lane]=vx; }
    } else if (wave == 3) {
        float va=0.f, vq=0.f, vx=0.f;
        if (lane >= 1 && lane <= MS) { float aa=at_[MS-lane]; va=aa; vq=aa*aa; vx=xt_[MS-lane]; }
#pragma unroll
        for (int d = 1; d < 64; d <<= 1) {
            float ya=__shfl_up(va,d), yq=__shfl_up(vq,d), yx=__shfl_up(vx,d);
            if (lane >= d) { va+=ya; vq+=yq; vx+=yx; }
        }
        if (lane <= MS) { At[lane]=va; Aqt[lane]=vq; Xt[lane]=vx; }
    }
    __syncthreads();                                   // B2
    fft2048(A2, B2, 16);  __syncthreads();             // B3
    fft2048(B2, A2, 64);  __syncthreads();             // B4
    fft2048(A2, B2, 256); __syncthreads();             // B5
    // FFT1 result in B2 (final radix-2 folded into the P/e/g computations)

    const float scl = sc[0], Cc = sc[1], mean = sc[2];
    const float Sa = sc[3], Qa = sc[4], Szz = sc[5];
    const float MSC = 0.5f * (1.0f / 2048.0f);

    // scan locals persist across intervals (waves 4-7)
    float se0=0,se1=0,se2=0,se3=0, sg0=0,sg1=0,sg2=0,sg3=0;
    float incE=0, incG=0, totE=0, totG=0;

    // ---- I5: fused unpack+Q-build+FFT2 s=1 (w0-3) || e/g + scan (w4-7) -----
    if (t < 256) {
        const int q = t;
        float2 wA = TW[q], wB = TW[q + 256];
        auto mkQ = [&](int k, float2 w, int ni) -> float2 {
            float2 Pa, Pb;
            if (k == 0) {
                float2 U = B2[0], V = B2[1024];
                float drx = U.x - V.x, dry = U.y - V.y;
                Pa = make_float2(0.f, 0.f);
                Pb = make_float2(4.f * drx * dry, 0.f);      // P[1024] (real)
            } else {
                float2 U = B2[k], V = B2[k + 1024];
                float2 R = B2[1024 - k], T = B2[2048 - k];
                // P[k]: zf = U+V, zg = R-T
                float zfr = U.x + V.x, zfi = U.y + V.y;
                float zgr = R.x - T.x, zgi = R.y - T.y;
                float hre = zfr + zgr, him = zfi - zgi;
                float sre = zfi + zgi, sim = zgr - zfr;
                Pa = make_float2(hre*sre + him*sim, -(him*sre - hre*sim));
                // P[1024-k]: zf' = R+T, zg' = U-V
                float zfr2 = R.x + T.x, zfi2 = R.y + T.y;
                float zgr2 = U.x - V.x, zgi2 = U.y - V.y;
                float hre2 = zfr2 + zgr2, him2 = zfi2 - zgi2;
                float sre2 = zfi2 + zgi2, sim2 = zgr2 - zfr2;
                Pb = make_float2(hre2*sre2 + him2*sim2, him2*sre2 - hre2*sim2);
            }
            float D1r = Pa.x + Pb.x, D1i = Pa.y + Pb.y;
            float D2r = Pa.x - Pb.x, D2i = Pa.y - Pb.y;
            float Er = D2r*w.x - D2i*w.y;
            float Ei = D2r*w.y + D2i*w.x;
            if (ni) return make_float2(D1r - Er, D1i - Ei);
            return make_float2(D1r + Ei, D1i - Er);
        };
        float2 x0 = mkQ(q,     wA, 0);
        float2 x1 = mkQ(q+256, wB, 0);
        float2 x2 = mkQ(q+512, wA, 1);
        float2 x3 = mkQ(q+768, wB, 1);
        float t0r=x0.x+x2.x, t0i=x0.y+x2.y;
        float t1r=x0.x-x2.x, t1i=x0.y-x2.y;
        float t2r=x1.x+x3.x, t2i=x1.y+x3.y;
        float d3r=x1.x-x3.x, d3i=x1.y-x3.y;
        float t3r=d3i, t3i=-d3r;
        float2 w1 = TW[2*q];
        float w2r=w1.x*w1.x-w1.y*w1.y, w2i=2.f*w1.x*w1.y;
        float w3r=w2r*w1.x-w2i*w1.y,  w3i=w2r*w1.y+w2i*w1.x;
        float y0r=t0r+t2r, y0i=t0i+t2i;
        float a1r=t1r+t3r, a1i=t1i+t3i;
        float y1r=a1r*w1.x-a1i*w1.y, y1i=a1r*w1.y+a1i*w1.x;
        float a2r=t0r-t2r, a2i=t0i-t2i;
        float y2r=a2r*w2r-a2i*w2i, y2i=a2r*w2i+a2i*w2r;
        float a3r=t1r-t3r, a3i=t1i-t3i;
        float y3r=a3r*w3r-a3i*w3i, y3i=a3r*w3i+a3i*w3r;
        Qlo[4*q]   = make_float2(y0r,y0i);
        Qlo[4*q+1] = make_float2(y1r,y1i);
        Qlo[4*q+2] = make_float2(y2r,y2i);
        Qlo[4*q+3] = make_float2(y3r,y3i);
    } else {
        int tt = t - 256;
        float ee[4], gg[4];
#pragma unroll
        for (int j = 0; j < 4; ++j) {
            int m = 4*tt + j;
            ee[j] = 0.f; gg[j] = 0.f;
            if (m < NMASK) {
                int f = m + KMIN;
                float zfr, zfi;
                if (f < 1024) { float2 U=B2[f], V=B2[f+1024]; zfr=U.x+V.x; zfi=U.y+V.y; }
                else          { float2 U=B2[0], V=B2[1024];   zfr=U.x-V.x; zfi=U.y-V.y; }
                int gi = 2048 - f;
                float2 p2 = B2[gi-1024], q3 = B2[gi];
                float zgr = p2.x - q3.x, zgi = p2.y - q3.y;
                float hre = zfr + zgr, him = zfi - zgi;
                float sre = zfi + zgi, sim = zgr - zfr;
                float hm = scl * sqrtf(hre*hre + him*him) * MSC;
                float sm = sqrtf(sre*sre + sim*sim) * MSC;
                ee[j] = 4.f*hm*hm; gg[j] = 4.f*hm*sm;
            }
        }
        se0=ee[0]; se1=se0+ee[1]; se2=se1+ee[2]; se3=se2+ee[3];
        sg0=gg[0]; sg1=sg0+gg[1]; sg2=sg1+gg[2]; sg3=sg2+gg[3];
        totE=se3; totG=sg3; incE=totE; incG=totG;
#pragma unroll
        for (int d = 1; d < 64; d <<= 1) {
            float yE=__shfl_up(incE,d), yG=__shfl_up(incG,d);
            if (lane >= d) { incE+=yE; incG+=yG; }
        }
        if (lane == 63) { wsA[wave-4]=incE; wsB[wave-4]=incG; }
    }
    __syncthreads();                                   // B6

    // ---- I6: FFT2 s=4 || scan writeback ----
    if (t < 256) { fft1024(Qlo, Qhi, 4); }
    else {
        int tt = t - 256, w4 = wave - 4;
        float offE=0.f, offG=0.f;
        for (int w = 0; w < w4; ++w) { offE+=wsA[w]; offG+=wsB[w]; }
        float preE = offE + incE - totE;
        float preG = offG + incG - totG;
        ((float4*)siA)[tt]  = make_float4(preE+se0, preE+se1, preE+se2, preE+se3);
        ((float4*)siBr)[tt] = make_float4(preG+sg0, preG+sg1, preG+sg2, preG+sg3);
    }
    __syncthreads();                                   // B7

    // ---- I7: FFT2 s=16 || searchsorted ----
    if (t < 256) { fft1024(Qhi, Qlo, 16); }
    else if (t < 256 + 17) {
        int tl = t - 256;
        float total = siA[NMASK-1];
        float bin = ((float)tl * (1.0f/16.0f)) * total;
        int lo = 0, hi = NMASK;
        while (lo < hi) { int mid=(lo+hi)>>1; if (siA[mid] <= bin) lo=mid+1; else hi=mid; }
        edges[tl] = (lo < NMASK-1) ? lo : (NMASK-1);
    }
    __syncthreads();                                   // B8

    // ---- I8: FFT2 s=64 || summ || wrap edge-sums ----
    if (t < 256) { fft1024(Qlo, Qhi, 64); }
    else {
        int idx = t - 256;
        if (idx < 16) {
            float total = siA[NMASK-1];
            float qf = 1.0f / sqrtf(total);
            float total2 = siBr[NMASK-1] * qf;
            float snr = (siBr[edges[idx+1]] - siBr[edges[idx]]) * qf;
            float d = snr - total2 * (1.0f/16.0f);
            summ[idx] = d * d;
        }
        int c = idx >> 1, k2 = idx & 1;
        if (c < NWIN) {
            int off = c - MS;
            float acc = 0.f;
            if (off > 0) {
                for (int j = k2; j < off; j += 2) acc += ah[j] * (xt_[MS-off+j] - mean);
            } else if (off < 0) {
                int o = -off;
                for (int j = k2; j < o; j += 2) acc += at_[MS-o+j] * (xhd[j] - mean);
            }
            acc += __shfl_down(acc, 1);
            if (k2 == 0) accv[c] = acc;
        }
    }
    __syncthreads();                                   // B9
    // FFT2 s=64 output in Qhi; final s=256 stage is twiddle-free -> fused below

    // ---- I9: wrap: inline final butterfly + affine Pearson -> corrv ----
    if (t < NWIN) {
        int c = t;
        int off = c - MS;
        int sidx = (off >= 0) ? off : (2048 + off);
        int n = sidx >> 1;
        int q = n & 255;
        float2 x0 = Qhi[q], x1 = Qhi[q+256], x2 = Qhi[q+512], x3 = Qhi[q+768];
        float2 Fv;
        if (n < 256) {       // j = 0: y0 = (x0+x2)+(x1+x3)
            Fv = make_float2((x0.x+x2.x)+(x1.x+x3.x), (x0.y+x2.y)+(x1.y+x3.y));
        } else {             // j = 3: y3 = t1 - t3,  t3 = (d3i, -d3r)
            float t1r_ = x0.x - x2.x, t1i_ = x0.y - x2.y;
            float d3r_ = x1.x - x3.x, d3i_ = x1.y - x3.y;
            Fv = make_float2(t1r_ - d3i_, t1i_ + d3r_);
        }
        float val = (sidx & 1) ? -Fv.y : Fv.x;
        float circ = val * (1.0f/8192.0f);
        float acc = accv[c];
        float Sin_a, Sin_q, Zex, nin;
        if (off >= 0) {
            Sin_a = Sa - Ah[off]; Sin_q = Qa - Aqh[off];
            Zex = Xt[off] - (float)off * mean; nin = 2048.0f - (float)off;
        } else {
            int o = -off;
            Sin_a = Sa - At[o]; Sin_q = Qa - Aqt[o];
            Zex = Xh[o] - (float)o * mean; nin = 2048.0f - (float)o;
        }
        float num = scl * (circ - acc) + Cc * Zex;
        float Sw  = scl * Sin_a - Cc * nin;
        float Sw2 = scl*scl*Sin_q - 2.f*scl*Cc*Sin_a + Cc*Cc*nin;
        float varw = Sw2 - Sw * Sw * (1.0f/2048.0f);
        corrv[c] = num / sqrtf(varw * Szz);
    }
    __syncthreads();                                   // B10

    // ---- I10: max reduce + output ----
    if (wave == 0) {
        float m = corrv[lane];
        if (lane + 64 < NWIN) m = fmaxf(m, corrv[lane + 64]);
#pragma unroll
        for (int d = 32; d; d >>= 1) m = fmaxf(m, __shfl_down(m, d));
        if (lane == 0) {
            float loss0 = (1.0f - m) / (1.0f + m);
            float ss = 0.f;
            for (int i = 0; i < 16; ++i) ss += summ[i];
            float chisq = 16.0f * ss / 15.0f;
            float c3 = chisq * chisq * chisq;
            out[r] = loss0 * powf(1.0f + c3, 1.0f/6.0f);
        }
    }
}

// ------------------------------------------------------------------
extern "C" void kernel_launch(void* const* d_in, const int* in_sizes, int n_in,
                              void* d_out, int out_size, void* d_ws, size_t ws_size,
                              hipStream_t stream) {
    const float* xhat = (const float*)d_in[0];
    const float* x    = (const float*)d_in[1];
    float* out = (float*)d_out;
    (void)in_sizes; (void)n_in; (void)out_size; (void)d_ws; (void)ws_size;

    fused_mfl_kernel<<<ROWS, 512, 0, stream>>>(xhat, x, out);
}

// Round 9
// 65.748 us; speedup vs baseline: 1.6425x; 1.0225x over previous
//
#include <hip/hip_runtime.h>
#include <math.h>

#define ROWS 512
#define DIM 2048
#define MS 51            // MAX_SHIFT
#define NWIN 103         // 2*MS+1
#define KMIN 32          // HIGHPASS bins
#define NMASK 993        // 1025-32

// One block (512 threads, 8 waves) per row. 9 barriers / 10 intervals.
//  I0: strided load + stats partials + head/tail stage + FFT1 r4 s=1 (regs)
//  I1: FFT1 r8 s=4 (w0-3) || stats reduce (w4) || prefix scans (w5,w6)
//  I2: FFT1 r8 s=32;  I3: FFT1 r8 s=256 (twiddle-free) -> full X in B2
//  I4: Q-build (direct X reads) + FFT2 s=1 (w0-3) || e/g + scan shfl (w4-7)
//  I5: FFT2 s=4 || scan writeback;  I6: s=16 || searchsorted
//  I7: s=64 || summ + wrap edge-sums;  I8: wrap (final r4 inline)
//  I9: max reduce -> out
__global__ __launch_bounds__(512) void fused_mfl_kernel(
    const float* __restrict__ xhat, const float* __restrict__ x,
    float* __restrict__ out)
{
    const int r = blockIdx.x;
    const int t = threadIdx.x;
    const int lane = t & 63;
    const int wave = t >> 6;          // 0..7

    __shared__ float smem[13056];     // 51 KB arena
    float2* A2  = (float2*)smem;                 // 2048 cplx [0,4096)
    float2* B2  = (float2*)(smem + 4096);        // 2048 cplx [4096,8192)
    float2* TW  = (float2*)(smem + 8192);        // 512 cplx  [8192,9216)
    float2* Qlo = (float2*)smem;                 // 1024 cplx [0,2048)
    float2* Qhi = (float2*)smem + 1024;          // 1024 cplx [2048,4096)
    float* siA  = smem + 4096;                   // 1024 (B2 region, post-I4)
    float* siBr = smem + 5120;                   // 1024
    float* red6 = smem + 9216;                   // 3072 (dead after I1)
    float* ah   = smem + 12288;                  // 51 raw a head
    float* xhd  = smem + 12339;                  // 51 raw x head
    float* at_  = smem + 12390;                  // 51 raw a tail
    float* xt_  = smem + 12441;                  // 51 raw x tail
    float* Ah   = smem + 12492;                  // 52 prefix sums
    float* Aqh  = smem + 12544;
    float* Xh   = smem + 12596;
    float* At   = smem + 12648;
    float* Aqt  = smem + 12700;
    float* Xt   = smem + 12752;
    float* corrv= smem + 12804;                  // 103
    float* accv = smem + 12907;                  // 103 wrap edge-sums

    __shared__ float sc[8];
    __shared__ int   edges[17];
    __shared__ float summ[16];
    __shared__ float wsA[4], wsB[4];

    const float* xhp = xhat + (size_t)r * DIM;
    const float* xrp = x    + (size_t)r * DIM;
    // strided load: thread t holds samples {t, t+512, t+1024, t+1536}
    float av[4] = {xhp[t], xhp[t+512], xhp[t+1024], xhp[t+1536]};
    float bv[4] = {xrp[t], xrp[t+512], xrp[t+1024], xrp[t+1536]};

    // twiddle: TW[u] = exp(-i*pi*u/1024); this thread's s=1 twiddle = TW[t]
    float swv, cwv;
    __sincosf((float)t * (-3.14159265358979323846f / 1024.0f), &swv, &cwv);
    TW[t] = make_float2(cwv, swv);

    // ---- I0: stats partials + head/tail + FFT1 r4 s=1 from registers -------
    {
        float mn4 = fminf(fminf(av[0],av[1]), fminf(av[2],av[3]));
        float mx4 = fmaxf(fmaxf(av[0],av[1]), fmaxf(av[2],av[3]));
        float sa = (av[0]+av[1])+(av[2]+av[3]);
        float qa = (av[0]*av[0]+av[1]*av[1])+(av[2]*av[2]+av[3]*av[3]);
        float sx = (bv[0]+bv[1])+(bv[2]+bv[3]);
        float qx = (bv[0]*bv[0]+bv[1]*bv[1])+(bv[2]*bv[2]+bv[3]*bv[3]);
        red6[t] = mn4; red6[512+t] = mx4; red6[1024+t] = sa;
        red6[1536+t] = qa; red6[2048+t] = sx; red6[2560+t] = qx;
    }
    if (t < MS)   { ah[t] = av[0];      xhd[t] = bv[0]; }
    if (t >= 461) { at_[t-461] = av[3]; xt_[t-461] = bv[3]; }  // samples 1997..2047
    {
        // radix-4 butterfly, s=1, u=q=t, w1 = (cwv,swv) local -> A2
        float t0r=av[0]+av[2], t0i=bv[0]+bv[2];
        float t1r=av[0]-av[2], t1i=bv[0]-bv[2];
        float t2r=av[1]+av[3], t2i=bv[1]+bv[3];
        float d3r=av[1]-av[3], d3i=bv[1]-bv[3];
        float t3r=d3i, t3i=-d3r;
        float w1r=cwv, w1i=swv;
        float w2r=w1r*w1r-w1i*w1i, w2i=2.f*w1r*w1i;
        float w3r=w2r*w1r-w2i*w1i, w3i=w2r*w1i+w2i*w1r;
        float y0r=t0r+t2r, y0i=t0i+t2i;
        float a1r=t1r+t3r, a1i=t1i+t3i;
        float y1r=a1r*w1r-a1i*w1i, y1i=a1r*w1i+a1i*w1r;
        float a2r=t0r-t2r, a2i=t0i-t2i;
        float y2r=a2r*w2r-a2i*w2i, y2i=a2r*w2i+a2i*w2r;
        float a3r=t1r-t3r, a3i=t1i-t3i;
        float y3r=a3r*w3r-a3i*w3i, y3i=a3r*w3i+a3i*w3r;
        A2[4*t]   = make_float2(y0r,y0i);
        A2[4*t+1] = make_float2(y1r,y1i);
        A2[4*t+2] = make_float2(y2r,y2i);
        A2[4*t+3] = make_float2(y3r,y3i);
    }
    __syncthreads();                                   // B1

    // 2048-pt radix-8 Stockham DIF stage (256 butterflies, t<256)
    auto fft2048_r8 = [&](const float2* Sp, float2* Dp, const int s, const bool tw) {
        const int q = t;
        const int u = q & ~(s - 1);
        float2 x0=Sp[q],      x1=Sp[q+256],  x2=Sp[q+512],  x3=Sp[q+768];
        float2 x4=Sp[q+1024], x5=Sp[q+1280], x6=Sp[q+1536], x7=Sp[q+1792];
        // A = DFT4(x0,x2,x4,x6)
        float e0r=x0.x+x4.x, e0i=x0.y+x4.y;
        float e1r=x0.x-x4.x, e1i=x0.y-x4.y;
        float e2r=x2.x+x6.x, e2i=x2.y+x6.y;
        float e3r=x2.x-x6.x, e3i=x2.y-x6.y;
        float A0r=e0r+e2r, A0i=e0i+e2i;
        float A1r=e1r+e3i, A1i=e1i-e3r;       // e1 - i*e3
        float A2r_=e0r-e2r, A2i_=e0i-e2i;
        float A3r=e1r-e3i, A3i=e1i+e3r;       // e1 + i*e3
        // B = DFT4(x1,x3,x5,x7)
        float o0r=x1.x+x5.x, o0i=x1.y+x5.y;
        float o1r=x1.x-x5.x, o1i=x1.y-x5.y;
        float o2r=x3.x+x7.x, o2i=x3.y+x7.y;
        float o3r=x3.x-x7.x, o3i=x3.y-x7.y;
        float B0r=o0r+o2r, B0i=o0i+o2i;
        float B1r=o1r+o3i, B1i=o1i-o3r;
        float B2r_=o0r-o2r, B2i_=o0i-o2i;
        float B3r=o1r-o3i, B3i=o1i+o3r;
        // rotations: C1 = W8*B1, C2 = -i*B2, C3 = W8^3*B3
        const float RT = 0.70710678118654752f;
        float C1r = RT*(B1r + B1i), C1i = RT*(B1i - B1r);
        float C2r = B2i_,           C2i = -B2r_;
        float C3r = RT*(B3i - B3r), C3i = -RT*(B3r + B3i);
        float y0r=A0r+B0r,  y0i=A0i+B0i;
        float y1r=A1r+C1r,  y1i=A1i+C1i;
        float y2r=A2r_+C2r, y2i=A2i_+C2i;
        float y3r=A3r+C3r,  y3i=A3i+C3i;
        float y4r=A0r-B0r,  y4i=A0i-B0i;
        float y5r=A1r-C1r,  y5i=A1i-C1i;
        float y6r=A2r_-C2r, y6i=A2i_-C2i;
        float y7r=A3r-C3r,  y7i=A3i-C3i;
        int base = q + 7*u;
        Dp[base] = make_float2(y0r, y0i);
        if (tw) {
            float2 w1 = TW[u];
            auto cm = [](float ar, float ai, float br, float bi, float* rr, float* ri) {
                *rr = ar*br - ai*bi; *ri = ar*bi + ai*br;
            };
            float w2r,w2i,w3r,w3i,w4r,w4i,w5r,w5i,w6r,w6i,w7r,w7i;
            cm(w1.x,w1.y,w1.x,w1.y,&w2r,&w2i);
            cm(w2r,w2i,w1.x,w1.y,&w3r,&w3i);
            cm(w2r,w2i,w2r,w2i,&w4r,&w4i);
            cm(w2r,w2i,w3r,w3i,&w5r,&w5i);
            cm(w3r,w3i,w3r,w3i,&w6r,&w6i);
            cm(w3r,w3i,w4r,w4i,&w7r,&w7i);
            float rr, ri;
            cm(y1r,y1i,w1.x,w1.y,&rr,&ri); Dp[base+s]   = make_float2(rr,ri);
            cm(y2r,y2i,w2r,w2i,&rr,&ri);   Dp[base+2*s] = make_float2(rr,ri);
            cm(y3r,y3i,w3r,w3i,&rr,&ri);   Dp[base+3*s] = make_float2(rr,ri);
            cm(y4r,y4i,w4r,w4i,&rr,&ri);   Dp[base+4*s] = make_float2(rr,ri);
            cm(y5r,y5i,w5r,w5i,&rr,&ri);   Dp[base+5*s] = make_float2(rr,ri);
            cm(y6r,y6i,w6r,w6i,&rr,&ri);   Dp[base+6*s] = make_float2(rr,ri);
            cm(y7r,y7i,w7r,w7i,&rr,&ri);   Dp[base+7*s] = make_float2(rr,ri);
        } else {
            Dp[base+s]   = make_float2(y1r,y1i);
            Dp[base+2*s] = make_float2(y2r,y2i);
            Dp[base+3*s] = make_float2(y3r,y3i);
            Dp[base+4*s] = make_float2(y4r,y4i);
            Dp[base+5*s] = make_float2(y5r,y5i);
            Dp[base+6*s] = make_float2(y6r,y6i);
            Dp[base+7*s] = make_float2(y7r,y7i);
        }
    };
    // 1024-pt radix-4 stage (t<256 only)
    auto fft1024 = [&](const float2* Sp, float2* Dp, const int s) {
        const int q = t;
        const int u = q & ~(s - 1);
        float2 x0 = Sp[q], x1 = Sp[q+256], x2 = Sp[q+512], x3 = Sp[q+768];
        float t0r=x0.x+x2.x, t0i=x0.y+x2.y;
        float t1r=x0.x-x2.x, t1i=x0.y-x2.y;
        float t2r=x1.x+x3.x, t2i=x1.y+x3.y;
        float d3r=x1.x-x3.x, d3i=x1.y-x3.y;
        float t3r=d3i, t3i=-d3r;
        float2 w1 = TW[2*u];
        float w2r=w1.x*w1.x-w1.y*w1.y, w2i=2.f*w1.x*w1.y;
        float w3r=w2r*w1.x-w2i*w1.y,  w3i=w2r*w1.y+w2i*w1.x;
        float y0r=t0r+t2r, y0i=t0i+t2i;
        float a1r=t1r+t3r, a1i=t1i+t3i;
        float y1r=a1r*w1.x-a1i*w1.y, y1i=a1r*w1.y+a1i*w1.x;
        float a2r=t0r-t2r, a2i=t0i-t2i;
        float y2r=a2r*w2r-a2i*w2i, y2i=a2r*w2i+a2i*w2r;
        float a3r=t1r-t3r, a3i=t1i-t3i;
        float y3r=a3r*w3r-a3i*w3i, y3i=a3r*w3i+a3i*w3r;
        int base = q + 3*u;
        Dp[base]     = make_float2(y0r,y0i);
        Dp[base+s]   = make_float2(y1r,y1i);
        Dp[base+2*s] = make_float2(y2r,y2i);
        Dp[base+3*s] = make_float2(y3r,y3i);
    };

    // ---- I1: FFT1 r8 s=4 (w0-3) || stats reduce (w4) || scans (w5,w6) ------
    if (t < 256) {
        fft2048_r8(A2, B2, 4, true);
    } else if (wave == 4) {
        float4 u, v;
        u=((const float4*)(red6     ))[2*lane]; v=((const float4*)(red6     ))[2*lane+1];
        float pmn=fminf(fminf(fminf(u.x,u.y),fminf(u.z,u.w)),fminf(fminf(v.x,v.y),fminf(v.z,v.w)));
        u=((const float4*)(red6+ 512))[2*lane]; v=((const float4*)(red6+ 512))[2*lane+1];
        float pmx=fmaxf(fmaxf(fmaxf(u.x,u.y),fmaxf(u.z,u.w)),fmaxf(fmaxf(v.x,v.y),fmaxf(v.z,v.w)));
        u=((const float4*)(red6+1024))[2*lane]; v=((const float4*)(red6+1024))[2*lane+1];
        float psa=((u.x+u.y)+(u.z+u.w))+((v.x+v.y)+(v.z+v.w));
        u=((const float4*)(red6+1536))[2*lane]; v=((const float4*)(red6+1536))[2*lane+1];
        float pqa=((u.x+u.y)+(u.z+u.w))+((v.x+v.y)+(v.z+v.w));
        u=((const float4*)(red6+2048))[2*lane]; v=((const float4*)(red6+2048))[2*lane+1];
        float psx=((u.x+u.y)+(u.z+u.w))+((v.x+v.y)+(v.z+v.w));
        u=((const float4*)(red6+2560))[2*lane]; v=((const float4*)(red6+2560))[2*lane+1];
        float pqx=((u.x+u.y)+(u.z+u.w))+((v.x+v.y)+(v.z+v.w));
#pragma unroll
        for (int d = 32; d; d >>= 1) {
            pmn=fminf(pmn,__shfl_down(pmn,d)); pmx=fmaxf(pmx,__shfl_down(pmx,d));
            psa+=__shfl_down(psa,d); pqa+=__shfl_down(pqa,d);
            psx+=__shfl_down(psx,d); pqx+=__shfl_down(pqx,d);
        }
        if (lane == 0) {
            float scl = 2.0f/(pmx - pmn);
            float Cc  = scl*pmn + 1.0f;          // y = scl*a - Cc
            float mean = psx * (1.0f/DIM);
            sc[0]=scl; sc[1]=Cc; sc[2]=mean; sc[3]=psa; sc[4]=pqa;
            sc[5]=pqx - (float)DIM*mean*mean;    // Szz
        }
    } else if (wave == 5) {
        float va=0.f, vq=0.f, vx=0.f;
        if (lane >= 1 && lane <= MS) { float aa=ah[lane-1]; va=aa; vq=aa*aa; vx=xhd[lane-1]; }
#pragma unroll
        for (int d = 1; d < 64; d <<= 1) {
            float ya=__shfl_up(va,d), yq=__shfl_up(vq,d), yx=__shfl_up(vx,d);
            if (lane >= d) { va+=ya; vq+=yq; vx+=yx; }
        }
        if (lane <= MS) { Ah[lane]=va; Aqh[lane]=vq; Xh[lane]=vx; }
    } else if (wave == 6) {
        float va=0.f, vq=0.f, vx=0.f;
        if (lane >= 1 && lane <= MS) { float aa=at_[MS-lane]; va=aa; vq=aa*aa; vx=xt_[MS-lane]; }
#pragma unroll
        for (int d = 1; d < 64; d <<= 1) {
            float ya=__shfl_up(va,d), yq=__shfl_up(vq,d), yx=__shfl_up(vx,d);
            if (lane >= d) { va+=ya; vq+=yq; vx+=yx; }
        }
        if (lane <= MS) { At[lane]=va; Aqt[lane]=vq; Xt[lane]=vx; }
    }
    __syncthreads();                                   // B2
    if (t < 256) { fft2048_r8(B2, A2, 32, true); }
    __syncthreads();                                   // B3
    if (t < 256) { fft2048_r8(A2, B2, 256, false); }   // twiddle-free final
    __syncthreads();                                   // B4
    // Full FFT1 result X in B2.

    const float scl = sc[0], Cc = sc[1], mean = sc[2];
    const float Sa = sc[3], Qa = sc[4], Szz = sc[5];
    const float MSC = 0.5f * (1.0f / 2048.0f);

    // scan locals persist across intervals (waves 4-7)
    float se0=0,se1=0,se2=0,se3=0, sg0=0,sg1=0,sg2=0,sg3=0;
    float incE=0, incG=0, totE=0, totG=0;

    // ---- I4: Q-build (direct X) + FFT2 s=1 (w0-3) || e/g + scan (w4-7) -----
    if (t < 256) {
        const int q = t;
        float2 wA = TW[q], wB = TW[q + 256];
        auto mkQ = [&](int k, float2 w, int ni) -> float2 {
            float2 Pa, Pb;
            if (k == 0) {
                float2 Xm = B2[1024];
                Pa = make_float2(0.f, 0.f);
                Pb = make_float2(4.f * Xm.x * Xm.y, 0.f);      // P[1024] (real)
            } else {
                float2 Xk = B2[k], Xn = B2[2048-k];
                float hre = Xk.x + Xn.x, him = Xk.y - Xn.y;
                float sre = Xk.y + Xn.y, sim = Xn.x - Xk.x;
                Pa = make_float2(hre*sre + him*sim, -(him*sre - hre*sim));
                float2 Xm = B2[1024-k], Xp = B2[1024+k];
                float hre2 = Xm.x + Xp.x, him2 = Xm.y - Xp.y;
                float sre2 = Xm.y + Xp.y, sim2 = Xp.x - Xm.x;
                Pb = make_float2(hre2*sre2 + him2*sim2, him2*sre2 - hre2*sim2);
            }
            float D1r = Pa.x + Pb.x, D1i = Pa.y + Pb.y;
            float D2r = Pa.x - Pb.x, D2i = Pa.y - Pb.y;
            float Er = D2r*w.x - D2i*w.y;
            float Ei = D2r*w.y + D2i*w.x;
            if (ni) return make_float2(D1r - Er, D1i - Ei);
            return make_float2(D1r + Ei, D1i - Er);
        };
        float2 x0 = mkQ(q,     wA, 0);
        float2 x1 = mkQ(q+256, wB, 0);
        float2 x2 = mkQ(q+512, wA, 1);
        float2 x3 = mkQ(q+768, wB, 1);
        float t0r=x0.x+x2.x, t0i=x0.y+x2.y;
        float t1r=x0.x-x2.x, t1i=x0.y-x2.y;
        float t2r=x1.x+x3.x, t2i=x1.y+x3.y;
        float d3r=x1.x-x3.x, d3i=x1.y-x3.y;
        float t3r=d3i, t3i=-d3r;
        float2 w1 = TW[2*q];
        float w2r=w1.x*w1.x-w1.y*w1.y, w2i=2.f*w1.x*w1.y;
        float w3r=w2r*w1.x-w2i*w1.y,  w3i=w2r*w1.y+w2i*w1.x;
        float y0r=t0r+t2r, y0i=t0i+t2i;
        float a1r=t1r+t3r, a1i=t1i+t3i;
        float y1r=a1r*w1.x-a1i*w1.y, y1i=a1r*w1.y+a1i*w1.x;
        float a2r=t0r-t2r, a2i=t0i-t2i;
        float y2r=a2r*w2r-a2i*w2i, y2i=a2r*w2i+a2i*w2r;
        float a3r=t1r-t3r, a3i=t1i-t3i;
        float y3r=a3r*w3r-a3i*w3i, y3i=a3r*w3i+a3i*w3r;
        Qlo[4*q]   = make_float2(y0r,y0i);
        Qlo[4*q+1] = make_float2(y1r,y1i);
        Qlo[4*q+2] = make_float2(y2r,y2i);
        Qlo[4*q+3] = make_float2(y3r,y3i);
    } else {
        int tt = t - 256;
        float ee[4], gg[4];
#pragma unroll
        for (int j = 0; j < 4; ++j) {
            int m = 4*tt + j;
            ee[j] = 0.f; gg[j] = 0.f;
            if (m < NMASK) {
                int f = m + KMIN;
                float2 Xf = B2[f], Xg = B2[2048-f];   // f=1024 -> both B2[1024]
                float hre = Xf.x + Xg.x, him = Xf.y - Xg.y;
                float sre = Xf.y + Xg.y, sim = Xg.x - Xf.x;
                float hm = scl * sqrtf(hre*hre + him*him) * MSC;
                float sm = sqrtf(sre*sre + sim*sim) * MSC;
                ee[j] = 4.f*hm*hm; gg[j] = 4.f*hm*sm;
            }
        }
        se0=ee[0]; se1=se0+ee[1]; se2=se1+ee[2]; se3=se2+ee[3];
        sg0=gg[0]; sg1=sg0+gg[1]; sg2=sg1+gg[2]; sg3=sg2+gg[3];
        totE=se3; totG=sg3; incE=totE; incG=totG;
#pragma unroll
        for (int d = 1; d < 64; d <<= 1) {
            float yE=__shfl_up(incE,d), yG=__shfl_up(incG,d);
            if (lane >= d) { incE+=yE; incG+=yG; }
        }
        if (lane == 63) { wsA[wave-4]=incE; wsB[wave-4]=incG; }
    }
    __syncthreads();                                   // B5

    // ---- I5: FFT2 s=4 || scan writeback ----
    if (t < 256) { fft1024(Qlo, Qhi, 4); }
    else {
        int tt = t - 256, w4 = wave - 4;
        float offE=0.f, offG=0.f;
        for (int w = 0; w < w4; ++w) { offE+=wsA[w]; offG+=wsB[w]; }
        float preE = offE + incE - totE;
        float preG = offG + incG - totG;
        ((float4*)siA)[tt]  = make_float4(preE+se0, preE+se1, preE+se2, preE+se3);
        ((float4*)siBr)[tt] = make_float4(preG+sg0, preG+sg1, preG+sg2, preG+sg3);
    }
    __syncthreads();                                   // B6

    // ---- I6: FFT2 s=16 || searchsorted ----
    if (t < 256) { fft1024(Qhi, Qlo, 16); }
    else if (t < 256 + 17) {
        int tl = t - 256;
        float total = siA[NMASK-1];
        float bin = ((float)tl * (1.0f/16.0f)) * total;
        int lo = 0, hi = NMASK;
        while (lo < hi) { int mid=(lo+hi)>>1; if (siA[mid] <= bin) lo=mid+1; else hi=mid; }
        edges[tl] = (lo < NMASK-1) ? lo : (NMASK-1);
    }
    __syncthreads();                                   // B7

    // ---- I7: FFT2 s=64 || summ || wrap edge-sums ----
    if (t < 256) { fft1024(Qlo, Qhi, 64); }
    else {
        int idx = t - 256;
        if (idx < 16) {
            float total = siA[NMASK-1];
            float qf = 1.0f / sqrtf(total);
            float total2 = siBr[NMASK-1] * qf;
            float snr = (siBr[edges[idx+1]] - siBr[edges[idx]]) * qf;
            float d = snr - total2 * (1.0f/16.0f);
            summ[idx] = d * d;
        }
        int c = idx >> 1, k2 = idx & 1;
        if (c < NWIN) {
            int off = c - MS;
            float acc = 0.f;
            if (off > 0) {
                for (int j = k2; j < off; j += 2) acc += ah[j] * (xt_[MS-off+j] - mean);
            } else if (off < 0) {
                int o = -off;
                for (int j = k2; j < o; j += 2) acc += at_[MS-o+j] * (xhd[j] - mean);
            }
            acc += __shfl_down(acc, 1);
            if (k2 == 0) accv[c] = acc;
        }
    }
    __syncthreads();                                   // B8
    // FFT2 s=64 output in Qhi; final s=256 stage is twiddle-free -> fused below

    // ---- I8: wrap: inline final butterfly + affine Pearson -> corrv ----
    if (t < NWIN) {
        int c = t;
        int off = c - MS;
        int sidx = (off >= 0) ? off : (2048 + off);
        int n = sidx >> 1;
        int q = n & 255;
        float2 x0 = Qhi[q], x1 = Qhi[q+256], x2 = Qhi[q+512], x3 = Qhi[q+768];
        float2 Fv;
        if (n < 256) {       // j = 0: y0 = (x0+x2)+(x1+x3)
            Fv = make_float2((x0.x+x2.x)+(x1.x+x3.x), (x0.y+x2.y)+(x1.y+x3.y));
        } else {             // j = 3: y3 = t1 - t3,  t3 = (d3i, -d3r)
            float t1r_ = x0.x - x2.x, t1i_ = x0.y - x2.y;
            float d3r_ = x1.x - x3.x, d3i_ = x1.y - x3.y;
            Fv = make_float2(t1r_ - d3i_, t1i_ + d3r_);
        }
        float val = (sidx & 1) ? -Fv.y : Fv.x;
        float circ = val * (1.0f/8192.0f);
        float acc = accv[c];
        float Sin_a, Sin_q, Zex, nin;
        if (off >= 0) {
            Sin_a = Sa - Ah[off]; Sin_q = Qa - Aqh[off];
            Zex = Xt[off] - (float)off * mean; nin = 2048.0f - (float)off;
        } else {
            int o = -off;
            Sin_a = Sa - At[o]; Sin_q = Qa - Aqt[o];
            Zex = Xh[o] - (float)o * mean; nin = 2048.0f - (float)o;
        }
        float num = scl * (circ - acc) + Cc * Zex;
        float Sw  = scl * Sin_a - Cc * nin;
        float Sw2 = scl*scl*Sin_q - 2.f*scl*Cc*Sin_a + Cc*Cc*nin;
        float varw = Sw2 - Sw * Sw * (1.0f/2048.0f);
        corrv[c] = num / sqrtf(varw * Szz);
    }
    __syncthreads();                                   // B9

    // ---- I9: max reduce + output ----
    if (wave == 0) {
        float m = corrv[lane];
        if (lane + 64 < NWIN) m = fmaxf(m, corrv[lane + 64]);
#pragma unroll
        for (int d = 32; d; d >>= 1) m = fmaxf(m, __shfl_down(m, d));
        if (lane == 0) {
            float loss0 = (1.0f - m) / (1.0f + m);
            float ss = 0.f;
            for (int i = 0; i < 16; ++i) ss += summ[i];
            float chisq = 16.0f * ss / 15.0f;
            float c3 = chisq * chisq * chisq;
            out[r] = loss0 * __powf(1.0f + c3, 1.0f/6.0f);
        }
    }
}

// ------------------------------------------------------------------
extern "C" void kernel_launch(void* const* d_in, const int* in_sizes, int n_in,
                              void* d_out, int out_size, void* d_ws, size_t ws_size,
                              hipStream_t stream) {
    const float* xhat = (const float*)d_in[0];
    const float* x    = (const float*)d_in[1];
    float* out = (float*)d_out;
    (void)in_sizes; (void)n_in; (void)out_size; (void)d_ws; (void)ws_size;

    fused_mfl_kernel<<<ROWS, 512, 0, stream>>>(xhat, x, out);
}